// Round 19
// baseline (1076.623 us; speedup 1.0000x reference)
//
#include <hip/hip_runtime.h>
#include <hip/hip_bf16.h>

typedef unsigned short u16;
typedef unsigned int u32;
typedef __attribute__((ext_vector_type(8))) short bf16x8;
typedef __attribute__((ext_vector_type(4))) short bf16x4;
typedef __attribute__((ext_vector_type(4))) float f32x4;
typedef __attribute__((ext_vector_type(4))) float float4v;

__device__ __forceinline__ float bf2f(u16 v) {
  union { u32 u; float f; } x; x.u = ((u32)v) << 16; return x.f;
}
__device__ __forceinline__ u16 f2bf(float f) {
  union { u32 u; float f; } x; x.f = f;
  return (u16)((x.u + 0x7fffu + ((x.u >> 16) & 1u)) >> 16);
}

__device__ __forceinline__ void gload16(const void* g, void* l) {
  __builtin_amdgcn_global_load_lds(
      (const __attribute__((address_space(1))) u32*)g,
      (__attribute__((address_space(3))) u32*)l, 16, 0, 0);
}

#define MFMA16(a, bfr, cacc) __builtin_amdgcn_mfma_f32_16x16x32_bf16((a), (bfr), (cacc), 0, 0, 0)

// ---------------- prep kernels ----------------

__global__ void convert_bf16_kernel(const float* __restrict__ in,
                                    u16* __restrict__ out, int n8) {
  int t = blockIdx.x * blockDim.x + threadIdx.x;
  if (t >= n8) return;
  const float4v* p = (const float4v*)(in + (size_t)t * 8);
  float4v a = p[0], b = p[1];
  union { bf16x8 v; u16 s[8]; } o;
  o.s[0] = f2bf(a[0]); o.s[1] = f2bf(a[1]); o.s[2] = f2bf(a[2]); o.s[3] = f2bf(a[3]);
  o.s[4] = f2bf(b[0]); o.s[5] = f2bf(b[1]); o.s[6] = f2bf(b[2]); o.s[7] = f2bf(b[3]);
  *(bf16x8*)(out + (size_t)t * 8) = o.v;
}

__global__ void transpose_kernel(const float* __restrict__ in, u16* __restrict__ out,
                                 int R, int C) {
  int t = blockIdx.x * blockDim.x + threadIdx.x;
  if (t >= R * C) return;
  int c = t / R, r = t % R;
  out[t] = f2bf(in[r * C + c]);
}

// maskT[wm][m][n] = mask[wm][n][m]  (fp32, coalesced writes)
__global__ void mask_t_kernel(const float* __restrict__ in, float* __restrict__ out) {
  int t = blockIdx.x * blockDim.x + threadIdx.x;
  if (t >= 64 * 4096) return;
  int wm = t >> 12, rest = t & 4095, m = rest >> 6, n = rest & 63;
  out[t] = in[wm * 4096 + n * 64 + m];
}

__global__ void bias_tab_kernel(const float* __restrict__ w1, const float* __restrict__ w2,
                                float* __restrict__ tab) {
  int t = blockIdx.x * blockDim.x + threadIdx.x;
  if (t >= 225 * 16) return;
  int r = t >> 4, h = t & 15;
  int i = r / 15, j = r % 15;
  float gi = (float)(i - 7) * (8.0f / 7.0f);
  float gj = (float)(j - 7) * (8.0f / 7.0f);
  float si = (gi > 0.f) ? 1.f : ((gi < 0.f) ? -1.f : 0.f);
  float sj = (gj > 0.f) ? 1.f : ((gj < 0.f) ? -1.f : 0.f);
  float t0 = si * log2f(fabsf(gi) + 1.0f) * (1.0f / 3.0f);
  float t1 = sj * log2f(fabsf(gj) + 1.0f) * (1.0f / 3.0f);
  float acc = 0.f;
  for (int k = 0; k < 512; ++k) {
    float a = t0 * w1[k] + t1 * w1[512 + k];
    float hs = a * fminf(fmaxf(a + 3.f, 0.f), 6.f) * (1.f / 6.f);
    acc += hs * w2[k * 16 + h];
  }
  tab[t] = acc;
}

// bias16T[h][m][n] = 16*sigmoid(tab[idx(n,m)][h])   (TRANSPOSED for vector loads)
__global__ void bias16_kernel(const float* __restrict__ tab, float* __restrict__ b16) {
  int t = blockIdx.x * blockDim.x + threadIdx.x;
  if (t >= 16 * 64 * 64) return;
  int h = t >> 12, nm = t & 4095, m = nm >> 6, n = nm & 63;
  int idx = ((n >> 3) - (m >> 3) + 7) * 15 + ((n & 7) - (m & 7) + 7);
  float b = tab[idx * 16 + h];
  b16[t] = 16.0f / (1.0f + expf(-b));
}

// ---------------- m97-style bf16 GEMM (generic, swizzled): out-projection ----------
template <bool F32OUT>
__global__ __launch_bounds__(256) void gemm_bt(const u16* __restrict__ A,
                                               const u16* __restrict__ Bt,
                                               void* __restrict__ Cout,
                                               int M, int N, int K) {
  __shared__ u16 lA[128 * 64];
  __shared__ u16 lB[128 * 64];
  const int tid = threadIdx.x;
  const int w = tid >> 6, l = tid & 63;
  const int lg = l >> 4, li = l & 15;
  const int nbn = N >> 7;
  const int nwg = gridDim.x;
  int bidx = blockIdx.x;
  int q = nwg >> 3, r = nwg & 7;
  int xcd = bidx & 7, pos = bidx >> 3;
  int swz = (xcd < r ? xcd * (q + 1) : r * (q + 1) + (xcd - r) * q) + pos;
  int bm = swz / nbn, bn = swz % nbn;
  const int wr = w >> 1, wc = w & 1;

  f32x4 acc[4][4];
#pragma unroll
  for (int i = 0; i < 4; i++)
#pragma unroll
    for (int j = 0; j < 4; j++) acc[i][j] = (f32x4){0.f, 0.f, 0.f, 0.f};

  const u16* Abase = A + (size_t)(bm * 128) * K;
  const u16* Bbase = Bt + (size_t)(bn * 128) * K;

  for (int k0 = 0; k0 < K; k0 += 64) {
#pragma unroll
    for (int i = 0; i < 4; ++i) {
      int c = w * 256 + i * 64 + l;
      int row = c >> 3, kc = c & 7;
      int kcs = kc ^ (row & 7);
      gload16(Abase + (size_t)row * K + k0 + kcs * 8, (u16*)lA + c * 8);
      gload16(Bbase + (size_t)row * K + k0 + kcs * 8, (u16*)lB + c * 8);
    }
    __syncthreads();
#pragma unroll
    for (int kk = 0; kk < 2; ++kk) {
      bf16x8 af[4], bfr[4];
#pragma unroll
      for (int t = 0; t < 4; ++t) {
        int row = wr * 64 + t * 16 + li;
        af[t] = *(const bf16x8*)&lA[row * 64 + (((kk * 4 + lg) ^ (row & 7)) << 3)];
        int col = wc * 64 + t * 16 + li;
        bfr[t] = *(const bf16x8*)&lB[col * 64 + (((kk * 4 + lg) ^ (col & 7)) << 3)];
      }
#pragma unroll
      for (int tm = 0; tm < 4; ++tm)
#pragma unroll
        for (int tn = 0; tn < 4; ++tn)
          acc[tm][tn] = MFMA16(af[tm], bfr[tn], acc[tm][tn]);
    }
    __syncthreads();
  }
  int r0 = bm * 128 + wr * 64 + lg * 4;
  int c0 = bn * 128 + wc * 64 + li;
#pragma unroll
  for (int tm = 0; tm < 4; ++tm)
#pragma unroll
    for (int tn = 0; tn < 4; ++tn)
#pragma unroll
      for (int j = 0; j < 4; ++j) {
        size_t off = (size_t)(r0 + tm * 16 + j) * N + c0 + tn * 16;
        if (F32OUT)
          ((float*)Cout)[off] = acc[tm][tn][j];
        else
          ((u16*)Cout)[off] = f2bf(acc[tm][tn][j]);
      }
}

// ---------------- 128^2 q/k GEMM + fused cosine-norm + head-major store -----------
__global__ __launch_bounds__(256) void gemm_qk(const u16* __restrict__ A,
                                               const u16* __restrict__ Bt,
                                               u16* __restrict__ Cq,
                                               const float* __restrict__ lscale,
                                               int M, int K) {
  __shared__ u16 lds[128 * 136];
  u16* lA = lds;
  u16* lB = lds + 8192;
  const int tid = threadIdx.x;
  const int w = tid >> 6, l = tid & 63;
  const int lg = l >> 4, li = l & 15;
  const int nbn = 8;
  const int nwg = gridDim.x;
  int bidx = blockIdx.x;
  int q = nwg >> 3, r = nwg & 7;
  int xcd = bidx & 7, pos = bidx >> 3;
  int swz = (xcd < r ? xcd * (q + 1) : r * (q + 1) + (xcd - r) * q) + pos;
  int bm = swz / nbn, bn = swz % nbn;
  const int wr = w >> 1, wc = w & 1;

  f32x4 acc[4][4];
#pragma unroll
  for (int i = 0; i < 4; i++)
#pragma unroll
    for (int j = 0; j < 4; j++) acc[i][j] = (f32x4){0.f, 0.f, 0.f, 0.f};

  const u16* Abase = A + (size_t)(bm * 128) * K;
  const u16* Bbase = Bt + (size_t)(bn * 128) * K;

  for (int k0 = 0; k0 < K; k0 += 64) {
#pragma unroll
    for (int i = 0; i < 4; ++i) {
      int c = w * 256 + i * 64 + l;
      int row = c >> 3, kc = c & 7;
      int kcs = kc ^ (row & 7);  // source pre-swizzle (rule 21)
      gload16(Abase + (size_t)row * K + k0 + kcs * 8, lA + c * 8);
      gload16(Bbase + (size_t)row * K + k0 + kcs * 8, lB + c * 8);
    }
    __syncthreads();
#pragma unroll
    for (int kk = 0; kk < 2; ++kk) {
      bf16x8 af[4], bfr[4];
#pragma unroll
      for (int t = 0; t < 4; ++t) {
        int row = wr * 64 + t * 16 + li;
        af[t] = *(const bf16x8*)&lA[row * 64 + (((kk * 4 + lg) ^ (row & 7)) << 3)];
        int col = wc * 64 + t * 16 + li;
        bfr[t] = *(const bf16x8*)&lB[col * 64 + (((kk * 4 + lg) ^ (col & 7)) << 3)];
      }
#pragma unroll
      for (int tm = 0; tm < 4; ++tm)
#pragma unroll
        for (int tn = 0; tn < 4; ++tn)
          acc[tm][tn] = MFMA16(af[tm], bfr[tn], acc[tm][tn]);
    }
    __syncthreads();
  }

  const int s_t = bn >> 2;          // 0=q 1=k
  const int hq = (bn & 3) * 4;
  float scv[2];
  if (s_t == 0) {
    scv[0] = __expf(fminf(lscale[hq + wc * 2 + 0], 4.6051702f));
    scv[1] = __expf(fminf(lscale[hq + wc * 2 + 1], 4.6051702f));
  } else {
    scv[0] = scv[1] = 1.0f;
  }
#pragma unroll
  for (int tm = 0; tm < 4; ++tm)
#pragma unroll
    for (int g = 0; g < 2; ++g) {
      f32x4 s2;
#pragma unroll
      for (int j = 0; j < 4; ++j)
        s2[j] = acc[tm][2 * g][j] * acc[tm][2 * g][j] +
                acc[tm][2 * g + 1][j] * acc[tm][2 * g + 1][j];
#pragma unroll
      for (int m = 1; m <= 8; m <<= 1)
#pragma unroll
        for (int j = 0; j < 4; ++j) s2[j] += __shfl_xor(s2[j], m);
#pragma unroll
      for (int j = 0; j < 4; ++j) {
        float rn = scv[g] / fmaxf(sqrtf(s2[j]), 1e-12f);
        acc[tm][2 * g][j] *= rn;
        acc[tm][2 * g + 1][j] *= rn;
      }
    }
  u16* ct = lds;
#pragma unroll
  for (int tm = 0; tm < 4; ++tm)
#pragma unroll
    for (int tn = 0; tn < 4; ++tn)
#pragma unroll
      for (int j = 0; j < 4; ++j)
        ct[(wr * 64 + tm * 16 + lg * 4 + j) * 136 + wc * 64 + tn * 16 + li] =
            f2bf(acc[tm][tn][j]);
  __syncthreads();
  {
    int rr = tid >> 2;
    int c8 = (tid & 3) * 8;
#pragma unroll
    for (int bh = 0; bh < 2; ++bh)
#pragma unroll
      for (int ht = 0; ht < 4; ++ht) {
        bf16x8 v = *(const bf16x8*)(ct + (bh * 64 + rr) * 136 + ht * 32 + c8);
        size_t base = ((size_t)(s_t * 16 + hq + ht) * 2048 + (bm * 2 + bh)) * 2048;
        *(bf16x8*)(Cq + base + rr * 32 + c8) = v;
      }
  }
}

// ---------------- 128^2 V GEMM + transposed store [32+h][b][d][n] -----------------
__global__ __launch_bounds__(256) void gemm_v(const u16* __restrict__ A,
                                              const u16* __restrict__ Bt,
                                              u16* __restrict__ Cq,
                                              int M, int K) {
  __shared__ u16 lds[128 * 136];
  u16* lA = lds;
  u16* lB = lds + 8192;
  const int tid = threadIdx.x;
  const int w = tid >> 6, l = tid & 63;
  const int lg = l >> 4, li = l & 15;
  const int nbn = 4;
  const int nwg = gridDim.x;
  int bidx = blockIdx.x;
  int q = nwg >> 3, r = nwg & 7;
  int xcd = bidx & 7, pos = bidx >> 3;
  int swz = (xcd < r ? xcd * (q + 1) : r * (q + 1) + (xcd - r) * q) + pos;
  int bm = swz / nbn, bn = swz % nbn;
  const int wr = w >> 1, wc = w & 1;

  f32x4 acc[4][4];
#pragma unroll
  for (int i = 0; i < 4; i++)
#pragma unroll
    for (int j = 0; j < 4; j++) acc[i][j] = (f32x4){0.f, 0.f, 0.f, 0.f};

  const u16* Abase = A + (size_t)(bm * 128) * K;
  const u16* Bbase = Bt + (size_t)(bn * 128) * K;

  for (int k0 = 0; k0 < K; k0 += 64) {
#pragma unroll
    for (int i = 0; i < 4; ++i) {
      int c = w * 256 + i * 64 + l;
      int row = c >> 3, kc = c & 7;
      int kcs = kc ^ (row & 7);
      gload16(Abase + (size_t)row * K + k0 + kcs * 8, lA + c * 8);
      gload16(Bbase + (size_t)row * K + k0 + kcs * 8, lB + c * 8);
    }
    __syncthreads();
#pragma unroll
    for (int kk = 0; kk < 2; ++kk) {
      bf16x8 af[4], bfr[4];
#pragma unroll
      for (int t = 0; t < 4; ++t) {
        int row = wr * 64 + t * 16 + li;
        af[t] = *(const bf16x8*)&lA[row * 64 + (((kk * 4 + lg) ^ (row & 7)) << 3)];
        int col = wc * 64 + t * 16 + li;
        bfr[t] = *(const bf16x8*)&lB[col * 64 + (((kk * 4 + lg) ^ (col & 7)) << 3)];
      }
#pragma unroll
      for (int tm = 0; tm < 4; ++tm)
#pragma unroll
        for (int tn = 0; tn < 4; ++tn)
          acc[tm][tn] = MFMA16(af[tm], bfr[tn], acc[tm][tn]);
    }
    __syncthreads();
  }

  const int hq = bn * 4;
  u16* ctT = lds;
#pragma unroll
  for (int tm = 0; tm < 4; ++tm)
#pragma unroll
    for (int tn = 0; tn < 4; ++tn)
#pragma unroll
      for (int j = 0; j < 4; ++j)
        ctT[(wc * 64 + tn * 16 + li) * 136 + wr * 64 + tm * 16 + lg * 4 + j] =
            f2bf(acc[tm][tn][j]);
  __syncthreads();
#pragma unroll
  for (int r2 = 0; r2 < 8; ++r2) {
    int id = r2 * 256 + tid;
    int colc = id >> 4;
    int seg = id & 15;
    bf16x8 v = *(const bf16x8*)&ctT[colc * 136 + seg * 8];
    int ht = colc >> 5, d = colc & 31;
    int wi = seg >> 3, n0 = (seg & 7) * 8;
    size_t base = ((size_t)(32 + hq + ht) * 2048 + (bm * 2 + wi)) * 2048;
    *(bf16x8*)(Cq + base + d * 64 + n0) = v;
  }
}

// ---------------- attention-only, occupancy-tuned ---------------------------------
// 8-key chunks: S [16h][8m][68n] f32 (34,816 B) + separate P16r [16h][64n][12m] u16
// (24,576 B) -> 59,392 B LDS, 2 barriers/chunk, launch_bounds(512,4) forces
// <=128 regs/lane -> 2 blocks/CU resident (was 1).
__global__ __launch_bounds__(512, 4) void attn2(const u16* __restrict__ qkv,
                                                const float* __restrict__ maskT,
                                                const float* __restrict__ bias16T,
                                                u16* __restrict__ aout) {
  __shared__ float S[16 * 544];    // [16h][8m][68n] f32 = 34,816 B
  __shared__ u16 P16r[16 * 768];   // [16h][64n][12m] u16 = 24,576 B (no alias)
  float* ob = S;                   // epilogue alias [16][516] f32 (33,024 B)
  const int tid = threadIdx.x;
  const int w = tid >> 6, l = tid & 63;
  const int lg = l >> 4, li = l & 15;
  const int b = blockIdx.x, wm = b & 63;
  const float* maskT_w = maskT + wm * 4096;

  // hoist Q fragments (loaded once, used in all 8 chunks)
  bf16x8 qfr[2][4];
#pragma unroll
  for (int hp = 0; hp < 2; ++hp) {
    const u16* qb = qkv + ((size_t)(w + hp * 8) * 2048 + b) * 2048;
#pragma unroll
    for (int tn = 0; tn < 4; ++tn)
      qfr[hp][tn] = *(const bf16x8*)(qb + (tn * 16 + li) * 32 + lg * 8);
  }

  f32x4 oacc[2][4][2];
#pragma unroll
  for (int hp = 0; hp < 2; ++hp)
#pragma unroll
    for (int i = 0; i < 4; ++i) {
      oacc[hp][i][0] = (f32x4){0.f, 0.f, 0.f, 0.f};
      oacc[hp][i][1] = (f32x4){0.f, 0.f, 0.f, 0.f};
    }

#pragma unroll 1
  for (int c = 0; c < 8; ++c) {
    // ---- QK^T 8-key chunk + bias + mask -> S (li<8 lanes write f32x4) ----
#pragma unroll
    for (int hp = 0; hp < 2; ++hp) {
      int h = w + hp * 8;
      const u16* kb = qkv + ((size_t)(16 + h) * 2048 + b) * 2048;
      const float* biasT_h = bias16T + h * 4096;
      bf16x8 kfc = *(const bf16x8*)(kb + (c * 8 + (li & 7)) * 32 + lg * 8);
      int mg = c * 8 + (li & 7);
#pragma unroll
      for (int tn = 0; tn < 4; ++tn) {
        f32x4 z = {0.f, 0.f, 0.f, 0.f};
        f32x4 s = MFMA16(qfr[hp][tn], kfc, z);
        if (li < 8) {
          float4v b4 = *(const float4v*)(biasT_h + mg * 64 + tn * 16 + lg * 4);
          float4v m4 = *(const float4v*)(maskT_w + mg * 64 + tn * 16 + lg * 4);
          *(float4v*)&S[h * 544 + li * 68 + tn * 16 + lg * 4] = s + b4 + m4;
        }
      }
    }
    __syncthreads();
    // ---- softmax over 16 heads: exactly 1 (m,n) point per thread ----
    {
      int m = tid >> 6, n = tid & 63;
      float vals[16];
      float mx = -3.0e38f;
#pragma unroll
      for (int hh = 0; hh < 16; ++hh) {
        vals[hh] = S[hh * 544 + m * 68 + n];
        mx = fmaxf(mx, vals[hh]);
      }
      float sum = 0.f;
#pragma unroll
      for (int hh = 0; hh < 16; ++hh) {
        float e = __expf(vals[hh] - mx);
        vals[hh] = e;
        sum += e;
      }
      float inv = 1.0f / sum;
#pragma unroll
      for (int hh = 0; hh < 16; ++hh)
        P16r[hh * 768 + n * 12 + m] = f2bf(vals[hh] * inv);
    }
    __syncthreads();
    // ---- PV (K=32 MFMA, keys beyond 8 zero); P via 2x b64, V^T via b128 ----
    // (no trailing barrier: next chunk's S writes touch a disjoint region)
#pragma unroll
    for (int hp = 0; hp < 2; ++hp) {
      int h = w + hp * 8;
      const u16* vbT = qkv + ((size_t)(32 + h) * 2048 + b) * 2048;
      bf16x8 vf;
      if (lg == 0) {
        // keys c*8..c*8+7 for d rows; td handled below via two loads
      }
#pragma unroll
      for (int tn = 0; tn < 4; ++tn) {
        bf16x8 pf;
        if (lg == 0) {
          const u16* pb = P16r + h * 768 + (tn * 16 + li) * 12;
          bf16x4 plo = *(const bf16x4*)pb;
          bf16x4 phi = *(const bf16x4*)(pb + 4);
          pf[0] = plo[0]; pf[1] = plo[1]; pf[2] = plo[2]; pf[3] = plo[3];
          pf[4] = phi[0]; pf[5] = phi[1]; pf[6] = phi[2]; pf[7] = phi[3];
        } else {
#pragma unroll
          for (int e = 0; e < 8; ++e) pf[e] = 0;
        }
#pragma unroll
        for (int td = 0; td < 2; ++td) {
          if (lg == 0)
            vf = *(const bf16x8*)(vbT + (td * 16 + li) * 64 + c * 8);
          else
#pragma unroll
            for (int e = 0; e < 8; ++e) vf[e] = 0;
          oacc[hp][tn][td] = MFMA16(pf, vf, oacc[hp][tn][td]);
        }
      }
    }
    __syncthreads();
  }

  // ---- epilogue: 4 row-passes through ob, coalesced stores ----
#pragma unroll
  for (int tn = 0; tn < 4; ++tn) {
#pragma unroll
    for (int hp = 0; hp < 2; ++hp) {
      int h = w + hp * 8;
#pragma unroll
      for (int td = 0; td < 2; ++td)
#pragma unroll
        for (int j = 0; j < 4; ++j)
          ob[(lg * 4 + j) * 516 + h * 32 + td * 16 + li] = oacc[hp][tn][td][j];
    }
    __syncthreads();
    {
      int rr = tid >> 5, c16 = (tid & 31) * 16;
      const float* src = ob + rr * 516 + c16;
      u16* dst = aout + ((size_t)b * 64 + tn * 16 + rr) * 512 + c16;
#pragma unroll
      for (int half = 0; half < 2; ++half) {
        union { bf16x8 v; u16 u[8]; } o;
#pragma unroll
        for (int e = 0; e < 8; ++e) o.u[e] = f2bf(src[half * 8 + e]);
        *(bf16x8*)(dst + half * 8) = o.v;
      }
    }
    __syncthreads();
  }
}

extern "C" void kernel_launch(void* const* d_in, const int* in_sizes, int n_in,
                              void* d_out, int out_size, void* d_ws, size_t ws_size,
                              hipStream_t stream) {
  const float* x = (const float*)d_in[0];
  const float* mask = (const float*)d_in[1];
  const float* w_qkv = (const float*)d_in[2];
  const float* w_out = (const float*)d_in[3];
  const float* cpb_w1 = (const float*)d_in[4];
  const float* cpb_w2 = (const float*)d_in[5];
  const float* lscale = (const float*)d_in[6];
  float* out = (float*)d_out;

  char* ws = (char*)d_ws;
  u16* wqkvT = (u16*)ws;                          // 1,572,864 B
  u16* woutT = (u16*)(ws + 1572864ull);           // 524,288 B
  float* btab = (float*)(ws + 2097152ull);        // 16,384 B
  float* b16 = (float*)(ws + 2113536ull);         // 262,144 B (transposed [h][m][n])
  float* maskT = (float*)(ws + 2375680ull);       // 16,777,216 B ([w][m][n])
  u16* qkv_ws = (u16*)(ws + 19152896ull);         // 402,653,184 B (head-major / V^T)
  u16* xb = (u16*)(ws + 19152896ull + 402653184ull);  // 134,217,728 B
  u16* attn_out = xb;  // alias: xb dead after gemm_qk/gemm_v; attn2 runs after

  // prep
  transpose_kernel<<<(512 * 1536 + 255) / 256, 256, 0, stream>>>(w_qkv, wqkvT, 512, 1536);
  transpose_kernel<<<(512 * 512 + 255) / 256, 256, 0, stream>>>(w_out, woutT, 512, 512);
  bias_tab_kernel<<<(225 * 16 + 255) / 256, 256, 0, stream>>>(cpb_w1, cpb_w2, btab);
  bias16_kernel<<<(16 * 64 * 64 + 255) / 256, 256, 0, stream>>>(btab, b16);
  mask_t_kernel<<<(64 * 4096 + 255) / 256, 256, 0, stream>>>(mask, maskT);

  // x -> bf16
  convert_bf16_kernel<<<(131072 * 64 + 255) / 256, 256, 0, stream>>>(x, xb, 131072 * 64);

  // q/k GEMM (fused norm/scale, head-major) and V GEMM (transposed) — split kernels
  gemm_qk<<<8192, 256, 0, stream>>>(xb, wqkvT, qkv_ws, lscale, 131072, 512);
  gemm_v<<<4096, 256, 0, stream>>>(xb, wqkvT + (size_t)1024 * 512, qkv_ws, 131072, 512);

  // attention (reads qkv_ws, writes attn_out == xb)
  attn2<<<2048, 512, 0, stream>>>(qkv_ws, maskT, b16, attn_out);

  // out = attn_out @ w_out (fp32 stores)
  gemm_bt<true><<<4096, 256, 0, stream>>>(attn_out, woutT, out, 131072, 512, 512);
}

// Round 20
// 895.199 us; speedup vs baseline: 1.2027x; 1.2027x over previous
//
#include <hip/hip_runtime.h>
#include <hip/hip_bf16.h>

typedef unsigned short u16;
typedef unsigned int u32;
typedef __attribute__((ext_vector_type(8))) short bf16x8;
typedef __attribute__((ext_vector_type(4))) short bf16x4;
typedef __attribute__((ext_vector_type(4))) float f32x4;
typedef __attribute__((ext_vector_type(4))) float float4v;

__device__ __forceinline__ float bf2f(u16 v) {
  union { u32 u; float f; } x; x.u = ((u32)v) << 16; return x.f;
}
__device__ __forceinline__ u16 f2bf(float f) {
  union { u32 u; float f; } x; x.f = f;
  return (u16)((x.u + 0x7fffu + ((x.u >> 16) & 1u)) >> 16);
}

__device__ __forceinline__ void gload16(const void* g, void* l) {
  __builtin_amdgcn_global_load_lds(
      (const __attribute__((address_space(1))) u32*)g,
      (__attribute__((address_space(3))) u32*)l, 16, 0, 0);
}

#define MFMA16(a, bfr, cacc) __builtin_amdgcn_mfma_f32_16x16x32_bf16((a), (bfr), (cacc), 0, 0, 0)

// ---------------- prep kernels ----------------

__global__ void convert_bf16_kernel(const float* __restrict__ in,
                                    u16* __restrict__ out, int n8) {
  int t = blockIdx.x * blockDim.x + threadIdx.x;
  if (t >= n8) return;
  const float4v* p = (const float4v*)(in + (size_t)t * 8);
  float4v a = p[0], b = p[1];
  union { bf16x8 v; u16 s[8]; } o;
  o.s[0] = f2bf(a[0]); o.s[1] = f2bf(a[1]); o.s[2] = f2bf(a[2]); o.s[3] = f2bf(a[3]);
  o.s[4] = f2bf(b[0]); o.s[5] = f2bf(b[1]); o.s[6] = f2bf(b[2]); o.s[7] = f2bf(b[3]);
  *(bf16x8*)(out + (size_t)t * 8) = o.v;
}

__global__ void transpose_kernel(const float* __restrict__ in, u16* __restrict__ out,
                                 int R, int C) {
  int t = blockIdx.x * blockDim.x + threadIdx.x;
  if (t >= R * C) return;
  int c = t / R, r = t % R;
  out[t] = f2bf(in[r * C + c]);
}

// maskT[wm][m][n] = mask[wm][n][m]  (fp32, coalesced writes)
__global__ void mask_t_kernel(const float* __restrict__ in, float* __restrict__ out) {
  int t = blockIdx.x * blockDim.x + threadIdx.x;
  if (t >= 64 * 4096) return;
  int wm = t >> 12, rest = t & 4095, m = rest >> 6, n = rest & 63;
  out[t] = in[wm * 4096 + n * 64 + m];
}

__global__ void bias_tab_kernel(const float* __restrict__ w1, const float* __restrict__ w2,
                                float* __restrict__ tab) {
  int t = blockIdx.x * blockDim.x + threadIdx.x;
  if (t >= 225 * 16) return;
  int r = t >> 4, h = t & 15;
  int i = r / 15, j = r % 15;
  float gi = (float)(i - 7) * (8.0f / 7.0f);
  float gj = (float)(j - 7) * (8.0f / 7.0f);
  float si = (gi > 0.f) ? 1.f : ((gi < 0.f) ? -1.f : 0.f);
  float sj = (gj > 0.f) ? 1.f : ((gj < 0.f) ? -1.f : 0.f);
  float t0 = si * log2f(fabsf(gi) + 1.0f) * (1.0f / 3.0f);
  float t1 = sj * log2f(fabsf(gj) + 1.0f) * (1.0f / 3.0f);
  float acc = 0.f;
  for (int k = 0; k < 512; ++k) {
    float a = t0 * w1[k] + t1 * w1[512 + k];
    float hs = a * fminf(fmaxf(a + 3.f, 0.f), 6.f) * (1.f / 6.f);
    acc += hs * w2[k * 16 + h];
  }
  tab[t] = acc;
}

// bias16T[h][m][n] = 16*sigmoid(tab[idx(n,m)][h])   (TRANSPOSED for vector loads)
__global__ void bias16_kernel(const float* __restrict__ tab, float* __restrict__ b16) {
  int t = blockIdx.x * blockDim.x + threadIdx.x;
  if (t >= 16 * 64 * 64) return;
  int h = t >> 12, nm = t & 4095, m = nm >> 6, n = nm & 63;
  int idx = ((n >> 3) - (m >> 3) + 7) * 15 + ((n & 7) - (m & 7) + 7);
  float b = tab[idx * 16 + h];
  b16[t] = 16.0f / (1.0f + expf(-b));
}

// ---------------- m97-style bf16 GEMM (generic, swizzled): out-projection ----------
template <bool F32OUT>
__global__ __launch_bounds__(256) void gemm_bt(const u16* __restrict__ A,
                                               const u16* __restrict__ Bt,
                                               void* __restrict__ Cout,
                                               int M, int N, int K) {
  __shared__ u16 lA[128 * 64];
  __shared__ u16 lB[128 * 64];
  const int tid = threadIdx.x;
  const int w = tid >> 6, l = tid & 63;
  const int lg = l >> 4, li = l & 15;
  const int nbn = N >> 7;
  const int nwg = gridDim.x;
  int bidx = blockIdx.x;
  int q = nwg >> 3, r = nwg & 7;
  int xcd = bidx & 7, pos = bidx >> 3;
  int swz = (xcd < r ? xcd * (q + 1) : r * (q + 1) + (xcd - r) * q) + pos;
  int bm = swz / nbn, bn = swz % nbn;
  const int wr = w >> 1, wc = w & 1;

  f32x4 acc[4][4];
#pragma unroll
  for (int i = 0; i < 4; i++)
#pragma unroll
    for (int j = 0; j < 4; j++) acc[i][j] = (f32x4){0.f, 0.f, 0.f, 0.f};

  const u16* Abase = A + (size_t)(bm * 128) * K;
  const u16* Bbase = Bt + (size_t)(bn * 128) * K;

  for (int k0 = 0; k0 < K; k0 += 64) {
#pragma unroll
    for (int i = 0; i < 4; ++i) {
      int c = w * 256 + i * 64 + l;
      int row = c >> 3, kc = c & 7;
      int kcs = kc ^ (row & 7);
      gload16(Abase + (size_t)row * K + k0 + kcs * 8, (u16*)lA + c * 8);
      gload16(Bbase + (size_t)row * K + k0 + kcs * 8, (u16*)lB + c * 8);
    }
    __syncthreads();
#pragma unroll
    for (int kk = 0; kk < 2; ++kk) {
      bf16x8 af[4], bfr[4];
#pragma unroll
      for (int t = 0; t < 4; ++t) {
        int row = wr * 64 + t * 16 + li;
        af[t] = *(const bf16x8*)&lA[row * 64 + (((kk * 4 + lg) ^ (row & 7)) << 3)];
        int col = wc * 64 + t * 16 + li;
        bfr[t] = *(const bf16x8*)&lB[col * 64 + (((kk * 4 + lg) ^ (col & 7)) << 3)];
      }
#pragma unroll
      for (int tm = 0; tm < 4; ++tm)
#pragma unroll
        for (int tn = 0; tn < 4; ++tn)
          acc[tm][tn] = MFMA16(af[tm], bfr[tn], acc[tm][tn]);
    }
    __syncthreads();
  }
  int r0 = bm * 128 + wr * 64 + lg * 4;
  int c0 = bn * 128 + wc * 64 + li;
#pragma unroll
  for (int tm = 0; tm < 4; ++tm)
#pragma unroll
    for (int tn = 0; tn < 4; ++tn)
#pragma unroll
      for (int j = 0; j < 4; ++j) {
        size_t off = (size_t)(r0 + tm * 16 + j) * N + c0 + tn * 16;
        if (F32OUT)
          ((float*)Cout)[off] = acc[tm][tn][j];
        else
          ((u16*)Cout)[off] = f2bf(acc[tm][tn][j]);
      }
}

// ---------------- 128^2 q/k GEMM + fused cosine-norm + head-major store -----------
__global__ __launch_bounds__(256) void gemm_qk(const u16* __restrict__ A,
                                               const u16* __restrict__ Bt,
                                               u16* __restrict__ Cq,
                                               const float* __restrict__ lscale,
                                               int M, int K) {
  __shared__ u16 lds[128 * 136];
  u16* lA = lds;
  u16* lB = lds + 8192;
  const int tid = threadIdx.x;
  const int w = tid >> 6, l = tid & 63;
  const int lg = l >> 4, li = l & 15;
  const int nbn = 8;
  const int nwg = gridDim.x;
  int bidx = blockIdx.x;
  int q = nwg >> 3, r = nwg & 7;
  int xcd = bidx & 7, pos = bidx >> 3;
  int swz = (xcd < r ? xcd * (q + 1) : r * (q + 1) + (xcd - r) * q) + pos;
  int bm = swz / nbn, bn = swz % nbn;
  const int wr = w >> 1, wc = w & 1;

  f32x4 acc[4][4];
#pragma unroll
  for (int i = 0; i < 4; i++)
#pragma unroll
    for (int j = 0; j < 4; j++) acc[i][j] = (f32x4){0.f, 0.f, 0.f, 0.f};

  const u16* Abase = A + (size_t)(bm * 128) * K;
  const u16* Bbase = Bt + (size_t)(bn * 128) * K;

  for (int k0 = 0; k0 < K; k0 += 64) {
#pragma unroll
    for (int i = 0; i < 4; ++i) {
      int c = w * 256 + i * 64 + l;
      int row = c >> 3, kc = c & 7;
      int kcs = kc ^ (row & 7);  // source pre-swizzle (rule 21)
      gload16(Abase + (size_t)row * K + k0 + kcs * 8, lA + c * 8);
      gload16(Bbase + (size_t)row * K + k0 + kcs * 8, lB + c * 8);
    }
    __syncthreads();
#pragma unroll
    for (int kk = 0; kk < 2; ++kk) {
      bf16x8 af[4], bfr[4];
#pragma unroll
      for (int t = 0; t < 4; ++t) {
        int row = wr * 64 + t * 16 + li;
        af[t] = *(const bf16x8*)&lA[row * 64 + (((kk * 4 + lg) ^ (row & 7)) << 3)];
        int col = wc * 64 + t * 16 + li;
        bfr[t] = *(const bf16x8*)&lB[col * 64 + (((kk * 4 + lg) ^ (col & 7)) << 3)];
      }
#pragma unroll
      for (int tm = 0; tm < 4; ++tm)
#pragma unroll
        for (int tn = 0; tn < 4; ++tn)
          acc[tm][tn] = MFMA16(af[tm], bfr[tn], acc[tm][tn]);
    }
    __syncthreads();
  }

  const int s_t = bn >> 2;          // 0=q 1=k
  const int hq = (bn & 3) * 4;
  float scv[2];
  if (s_t == 0) {
    scv[0] = __expf(fminf(lscale[hq + wc * 2 + 0], 4.6051702f));
    scv[1] = __expf(fminf(lscale[hq + wc * 2 + 1], 4.6051702f));
  } else {
    scv[0] = scv[1] = 1.0f;
  }
#pragma unroll
  for (int tm = 0; tm < 4; ++tm)
#pragma unroll
    for (int g = 0; g < 2; ++g) {
      f32x4 s2;
#pragma unroll
      for (int j = 0; j < 4; ++j)
        s2[j] = acc[tm][2 * g][j] * acc[tm][2 * g][j] +
                acc[tm][2 * g + 1][j] * acc[tm][2 * g + 1][j];
#pragma unroll
      for (int m = 1; m <= 8; m <<= 1)
#pragma unroll
        for (int j = 0; j < 4; ++j) s2[j] += __shfl_xor(s2[j], m);
#pragma unroll
      for (int j = 0; j < 4; ++j) {
        float rn = scv[g] / fmaxf(sqrtf(s2[j]), 1e-12f);
        acc[tm][2 * g][j] *= rn;
        acc[tm][2 * g + 1][j] *= rn;
      }
    }
  u16* ct = lds;
#pragma unroll
  for (int tm = 0; tm < 4; ++tm)
#pragma unroll
    for (int tn = 0; tn < 4; ++tn)
#pragma unroll
      for (int j = 0; j < 4; ++j)
        ct[(wr * 64 + tm * 16 + lg * 4 + j) * 136 + wc * 64 + tn * 16 + li] =
            f2bf(acc[tm][tn][j]);
  __syncthreads();
  {
    int rr = tid >> 2;
    int c8 = (tid & 3) * 8;
#pragma unroll
    for (int bh = 0; bh < 2; ++bh)
#pragma unroll
      for (int ht = 0; ht < 4; ++ht) {
        bf16x8 v = *(const bf16x8*)(ct + (bh * 64 + rr) * 136 + ht * 32 + c8);
        size_t base = ((size_t)(s_t * 16 + hq + ht) * 2048 + (bm * 2 + bh)) * 2048;
        *(bf16x8*)(Cq + base + rr * 32 + c8) = v;
      }
  }
}

// ---------------- 128^2 V GEMM + transposed store [32+h][b][d][n] -----------------
__global__ __launch_bounds__(256) void gemm_v(const u16* __restrict__ A,
                                              const u16* __restrict__ Bt,
                                              u16* __restrict__ Cq,
                                              int M, int K) {
  __shared__ u16 lds[128 * 136];
  u16* lA = lds;
  u16* lB = lds + 8192;
  const int tid = threadIdx.x;
  const int w = tid >> 6, l = tid & 63;
  const int lg = l >> 4, li = l & 15;
  const int nbn = 4;
  const int nwg = gridDim.x;
  int bidx = blockIdx.x;
  int q = nwg >> 3, r = nwg & 7;
  int xcd = bidx & 7, pos = bidx >> 3;
  int swz = (xcd < r ? xcd * (q + 1) : r * (q + 1) + (xcd - r) * q) + pos;
  int bm = swz / nbn, bn = swz % nbn;
  const int wr = w >> 1, wc = w & 1;

  f32x4 acc[4][4];
#pragma unroll
  for (int i = 0; i < 4; i++)
#pragma unroll
    for (int j = 0; j < 4; j++) acc[i][j] = (f32x4){0.f, 0.f, 0.f, 0.f};

  const u16* Abase = A + (size_t)(bm * 128) * K;
  const u16* Bbase = Bt + (size_t)(bn * 128) * K;

  for (int k0 = 0; k0 < K; k0 += 64) {
#pragma unroll
    for (int i = 0; i < 4; ++i) {
      int c = w * 256 + i * 64 + l;
      int row = c >> 3, kc = c & 7;
      int kcs = kc ^ (row & 7);
      gload16(Abase + (size_t)row * K + k0 + kcs * 8, lA + c * 8);
      gload16(Bbase + (size_t)row * K + k0 + kcs * 8, lB + c * 8);
    }
    __syncthreads();
#pragma unroll
    for (int kk = 0; kk < 2; ++kk) {
      bf16x8 af[4], bfr[4];
#pragma unroll
      for (int t = 0; t < 4; ++t) {
        int row = wr * 64 + t * 16 + li;
        af[t] = *(const bf16x8*)&lA[row * 64 + (((kk * 4 + lg) ^ (row & 7)) << 3)];
        int col = wc * 64 + t * 16 + li;
        bfr[t] = *(const bf16x8*)&lB[col * 64 + (((kk * 4 + lg) ^ (col & 7)) << 3)];
      }
#pragma unroll
      for (int tm = 0; tm < 4; ++tm)
#pragma unroll
        for (int tn = 0; tn < 4; ++tn)
          acc[tm][tn] = MFMA16(af[tm], bfr[tn], acc[tm][tn]);
    }
    __syncthreads();
  }

  const int hq = bn * 4;
  u16* ctT = lds;
#pragma unroll
  for (int tm = 0; tm < 4; ++tm)
#pragma unroll
    for (int tn = 0; tn < 4; ++tn)
#pragma unroll
      for (int j = 0; j < 4; ++j)
        ctT[(wc * 64 + tn * 16 + li) * 136 + wr * 64 + tm * 16 + lg * 4 + j] =
            f2bf(acc[tm][tn][j]);
  __syncthreads();
#pragma unroll
  for (int r2 = 0; r2 < 8; ++r2) {
    int id = r2 * 256 + tid;
    int colc = id >> 4;
    int seg = id & 15;
    bf16x8 v = *(const bf16x8*)&ctT[colc * 136 + seg * 8];
    int ht = colc >> 5, d = colc & 31;
    int wi = seg >> 3, n0 = (seg & 7) * 8;
    size_t base = ((size_t)(32 + hq + ht) * 2048 + (bm * 2 + wi)) * 2048;
    *(bf16x8*)(Cq + base + d * 64 + n0) = v;
  }
}

// ---------------- attention-only: q,k head-major [h][b][n][d]; V^T [h][b][d][n] ----
// Two-phase softmax (vals in regs) + n-major compact P16r [16h][64n][20m] u16
// (aliases S after a barrier) -> PV P-frags via 2x ds_read_b64, conflict-free.
__global__ __launch_bounds__(512, 2) void attn2(const u16* __restrict__ qkv,
                                                const float* __restrict__ maskT,
                                                const float* __restrict__ bias16T,
                                                u16* __restrict__ aout) {
  __shared__ float S[16 * 1088];     // [h][m(16)][68-pad n] f32 = 69,632 B
  u16* P16r = (u16*)S;               // phase B alias: [16h][64n][20m] u16 = 40,960 B
  float* ob = S;                     // epilogue alias [16][516] f32
  const int tid = threadIdx.x;
  const int w = tid >> 6, l = tid & 63;
  const int lg = l >> 4, li = l & 15;
  const int b = blockIdx.x, wm = b & 63;
  const float* maskT_w = maskT + wm * 4096;

  // hoist Q fragments (loaded once, used in all 4 chunks)
  bf16x8 qfr[2][4];
#pragma unroll
  for (int hp = 0; hp < 2; ++hp) {
    const u16* qb = qkv + ((size_t)(w + hp * 8) * 2048 + b) * 2048;
#pragma unroll
    for (int tn = 0; tn < 4; ++tn)
      qfr[hp][tn] = *(const bf16x8*)(qb + (tn * 16 + li) * 32 + lg * 8);
  }

  f32x4 oacc[2][4][2];
#pragma unroll
  for (int hp = 0; hp < 2; ++hp)
#pragma unroll
    for (int i = 0; i < 4; ++i) {
      oacc[hp][i][0] = (f32x4){0.f, 0.f, 0.f, 0.f};
      oacc[hp][i][1] = (f32x4){0.f, 0.f, 0.f, 0.f};
    }

#pragma unroll
  for (int c = 0; c < 4; ++c) {
    // ---- QK^T chunk (16 keys) + bias + mask -> S (float4 loads, b128 writes) ----
#pragma unroll
    for (int hp = 0; hp < 2; ++hp) {
      int h = w + hp * 8;
      const u16* kb = qkv + ((size_t)(16 + h) * 2048 + b) * 2048;
      const float* biasT_h = bias16T + h * 4096;
      bf16x8 kfc = *(const bf16x8*)(kb + (c * 16 + li) * 32 + lg * 8);
      int mg = c * 16 + li;
#pragma unroll
      for (int tn = 0; tn < 4; ++tn) {
        f32x4 z = {0.f, 0.f, 0.f, 0.f};
        f32x4 s = MFMA16(qfr[hp][tn], kfc, z);
        float4v b4 = *(const float4v*)(biasT_h + mg * 64 + tn * 16 + lg * 4);
        float4v m4 = *(const float4v*)(maskT_w + mg * 64 + tn * 16 + lg * 4);
        *(float4v*)&S[h * 1088 + li * 68 + tn * 16 + lg * 4] = s + b4 + m4;
      }
    }
    __syncthreads();
    // ---- softmax phase A: read S into regs, exp + inv (no LDS writes yet) ----
    float vals[2][16];
    float inv[2];
#pragma unroll
    for (int pp = 0; pp < 2; ++pp) {
      int p = tid + pp * 512;
      int base = (p >> 6) * 68 + (p & 63);
      float mx = -3.0e38f;
#pragma unroll
      for (int hh = 0; hh < 16; ++hh) {
        vals[pp][hh] = S[hh * 1088 + base];
        mx = fmaxf(mx, vals[pp][hh]);
      }
      float sum = 0.f;
#pragma unroll
      for (int hh = 0; hh < 16; ++hh) {
        float e = __expf(vals[pp][hh] - mx);
        vals[pp][hh] = e;
        sum += e;
      }
      inv[pp] = 1.0f / sum;
    }
    __syncthreads();  // all S reads done; safe to overwrite with P16r
    // ---- softmax phase B: write compact n-major P16r[h][n][20m] ----
#pragma unroll
    for (int pp = 0; pp < 2; ++pp) {
      int p = tid + pp * 512;
      int m = p >> 6, n = p & 63;
#pragma unroll
      for (int hh = 0; hh < 16; ++hh)
        P16r[hh * 1280 + n * 20 + m] = f2bf(vals[pp][hh] * inv[pp]);
    }
    __syncthreads();
    // ---- PV (K=32 MFMA, upper 16 keys zero); P via b64, V^T via b128 ----
#pragma unroll
    for (int hp = 0; hp < 2; ++hp) {
      int h = w + hp * 8;
      const u16* vbT = qkv + ((size_t)(32 + h) * 2048 + b) * 2048;
      bf16x8 vf[2];
      if (lg < 2) {
#pragma unroll
        for (int td = 0; td < 2; ++td)
          vf[td] = *(const bf16x8*)(vbT + (td * 16 + li) * 64 + c * 16 + lg * 8);
      } else {
#pragma unroll
        for (int td = 0; td < 2; ++td)
#pragma unroll
          for (int e = 0; e < 8; ++e) vf[td][e] = 0;
      }
#pragma unroll
      for (int tn = 0; tn < 4; ++tn) {
        bf16x8 pf;
        if (lg < 2) {
          const u16* pb = P16r + h * 1280 + (tn * 16 + li) * 20 + lg * 8;
          bf16x4 plo = *(const bf16x4*)pb;
          bf16x4 phi = *(const bf16x4*)(pb + 4);
          pf[0] = plo[0]; pf[1] = plo[1]; pf[2] = plo[2]; pf[3] = plo[3];
          pf[4] = phi[0]; pf[5] = phi[1]; pf[6] = phi[2]; pf[7] = phi[3];
        } else {
#pragma unroll
          for (int e = 0; e < 8; ++e) pf[e] = 0;
        }
        oacc[hp][tn][0] = MFMA16(pf, vf[0], oacc[hp][tn][0]);
        oacc[hp][tn][1] = MFMA16(pf, vf[1], oacc[hp][tn][1]);
      }
    }
    __syncthreads();  // P16r reads done; next chunk overwrites S region
  }

  // ---- epilogue: 4 row-passes through ob, coalesced stores ----
#pragma unroll
  for (int tn = 0; tn < 4; ++tn) {
#pragma unroll
    for (int hp = 0; hp < 2; ++hp) {
      int h = w + hp * 8;
#pragma unroll
      for (int td = 0; td < 2; ++td)
#pragma unroll
        for (int j = 0; j < 4; ++j)
          ob[(lg * 4 + j) * 516 + h * 32 + td * 16 + li] = oacc[hp][tn][td][j];
    }
    __syncthreads();
    {
      int rr = tid >> 5, c16 = (tid & 31) * 16;
      const float* src = ob + rr * 516 + c16;
      u16* dst = aout + ((size_t)b * 64 + tn * 16 + rr) * 512 + c16;
#pragma unroll
      for (int half = 0; half < 2; ++half) {
        union { bf16x8 v; u16 u[8]; } o;
#pragma unroll
        for (int e = 0; e < 8; ++e) o.u[e] = f2bf(src[half * 8 + e]);
        *(bf16x8*)(dst + half * 8) = o.v;
      }
    }
    __syncthreads();
  }
}

extern "C" void kernel_launch(void* const* d_in, const int* in_sizes, int n_in,
                              void* d_out, int out_size, void* d_ws, size_t ws_size,
                              hipStream_t stream) {
  const float* x = (const float*)d_in[0];
  const float* mask = (const float*)d_in[1];
  const float* w_qkv = (const float*)d_in[2];
  const float* w_out = (const float*)d_in[3];
  const float* cpb_w1 = (const float*)d_in[4];
  const float* cpb_w2 = (const float*)d_in[5];
  const float* lscale = (const float*)d_in[6];
  float* out = (float*)d_out;

  char* ws = (char*)d_ws;
  u16* wqkvT = (u16*)ws;                          // 1,572,864 B
  u16* woutT = (u16*)(ws + 1572864ull);           // 524,288 B
  float* btab = (float*)(ws + 2097152ull);        // 16,384 B
  float* b16 = (float*)(ws + 2113536ull);         // 262,144 B (transposed [h][m][n])
  float* maskT = (float*)(ws + 2375680ull);       // 16,777,216 B ([w][m][n])
  u16* qkv_ws = (u16*)(ws + 19152896ull);         // 402,653,184 B (head-major / V^T)
  u16* xb = (u16*)(ws + 19152896ull + 402653184ull);  // 134,217,728 B
  u16* attn_out = xb;  // alias: xb dead after gemm_qk/gemm_v; attn2 runs after

  // prep
  transpose_kernel<<<(512 * 1536 + 255) / 256, 256, 0, stream>>>(w_qkv, wqkvT, 512, 1536);
  transpose_kernel<<<(512 * 512 + 255) / 256, 256, 0, stream>>>(w_out, woutT, 512, 512);
  bias_tab_kernel<<<(225 * 16 + 255) / 256, 256, 0, stream>>>(cpb_w1, cpb_w2, btab);
  bias16_kernel<<<(16 * 64 * 64 + 255) / 256, 256, 0, stream>>>(btab, b16);
  mask_t_kernel<<<(64 * 4096 + 255) / 256, 256, 0, stream>>>(mask, maskT);

  // x -> bf16
  convert_bf16_kernel<<<(131072 * 64 + 255) / 256, 256, 0, stream>>>(x, xb, 131072 * 64);

  // q/k GEMM (fused norm/scale, head-major) and V GEMM (transposed) — split kernels
  gemm_qk<<<8192, 256, 0, stream>>>(xb, wqkvT, qkv_ws, lscale, 131072, 512);
  gemm_v<<<4096, 256, 0, stream>>>(xb, wqkvT + (size_t)1024 * 512, qkv_ws, 131072, 512);

  // attention (reads qkv_ws, writes attn_out == xb)
  attn2<<<2048, 512, 0, stream>>>(qkv_ws, maskT, b16, attn_out);

  // out = attn_out @ w_out (fp32 stores)
  gemm_bt<true><<<4096, 256, 0, stream>>>(attn_out, woutT, out, 131072, 512, 512);
}

// Round 21
// 849.247 us; speedup vs baseline: 1.2677x; 1.0541x over previous
//
#include <hip/hip_runtime.h>
#include <hip/hip_bf16.h>

typedef unsigned short u16;
typedef unsigned int u32;
typedef __attribute__((ext_vector_type(8))) short bf16x8;
typedef __attribute__((ext_vector_type(4))) short bf16x4;
typedef __attribute__((ext_vector_type(4))) float f32x4;
typedef __attribute__((ext_vector_type(4))) float float4v;

__device__ __forceinline__ float bf2f(u16 v) {
  union { u32 u; float f; } x; x.u = ((u32)v) << 16; return x.f;
}
__device__ __forceinline__ u16 f2bf(float f) {
  union { u32 u; float f; } x; x.f = f;
  return (u16)((x.u + 0x7fffu + ((x.u >> 16) & 1u)) >> 16);
}

__device__ __forceinline__ void gload16(const void* g, void* l) {
  __builtin_amdgcn_global_load_lds(
      (const __attribute__((address_space(1))) u32*)g,
      (__attribute__((address_space(3))) u32*)l, 16, 0, 0);
}

#define MFMA16(a, bfr, cacc) __builtin_amdgcn_mfma_f32_16x16x32_bf16((a), (bfr), (cacc), 0, 0, 0)

// K is compile-time everywhere (512) so the K-loop fully unrolls: staging bases are
// loop-invariant, per-iter +k0 folds into global_load imm offsets, LDS read addrs CSE.
constexpr int KDIM = 512;

// ---------------- prep kernels ----------------

__global__ void convert_bf16_kernel(const float* __restrict__ in,
                                    u16* __restrict__ out, int n8) {
  int t = blockIdx.x * blockDim.x + threadIdx.x;
  if (t >= n8) return;
  const float4v* p = (const float4v*)(in + (size_t)t * 8);
  float4v a = p[0], b = p[1];
  union { bf16x8 v; u16 s[8]; } o;
  o.s[0] = f2bf(a[0]); o.s[1] = f2bf(a[1]); o.s[2] = f2bf(a[2]); o.s[3] = f2bf(a[3]);
  o.s[4] = f2bf(b[0]); o.s[5] = f2bf(b[1]); o.s[6] = f2bf(b[2]); o.s[7] = f2bf(b[3]);
  *(bf16x8*)(out + (size_t)t * 8) = o.v;
}

__global__ void transpose_kernel(const float* __restrict__ in, u16* __restrict__ out,
                                 int R, int C) {
  int t = blockIdx.x * blockDim.x + threadIdx.x;
  if (t >= R * C) return;
  int c = t / R, r = t % R;
  out[t] = f2bf(in[r * C + c]);
}

// maskT[wm][m][n] = mask[wm][n][m]  (fp32, coalesced writes)
__global__ void mask_t_kernel(const float* __restrict__ in, float* __restrict__ out) {
  int t = blockIdx.x * blockDim.x + threadIdx.x;
  if (t >= 64 * 4096) return;
  int wm = t >> 12, rest = t & 4095, m = rest >> 6, n = rest & 63;
  out[t] = in[wm * 4096 + n * 64 + m];
}

__global__ void bias_tab_kernel(const float* __restrict__ w1, const float* __restrict__ w2,
                                float* __restrict__ tab) {
  int t = blockIdx.x * blockDim.x + threadIdx.x;
  if (t >= 225 * 16) return;
  int r = t >> 4, h = t & 15;
  int i = r / 15, j = r % 15;
  float gi = (float)(i - 7) * (8.0f / 7.0f);
  float gj = (float)(j - 7) * (8.0f / 7.0f);
  float si = (gi > 0.f) ? 1.f : ((gi < 0.f) ? -1.f : 0.f);
  float sj = (gj > 0.f) ? 1.f : ((gj < 0.f) ? -1.f : 0.f);
  float t0 = si * log2f(fabsf(gi) + 1.0f) * (1.0f / 3.0f);
  float t1 = sj * log2f(fabsf(gj) + 1.0f) * (1.0f / 3.0f);
  float acc = 0.f;
  for (int k = 0; k < 512; ++k) {
    float a = t0 * w1[k] + t1 * w1[512 + k];
    float hs = a * fminf(fmaxf(a + 3.f, 0.f), 6.f) * (1.f / 6.f);
    acc += hs * w2[k * 16 + h];
  }
  tab[t] = acc;
}

// bias16T[h][m][n] = 16*sigmoid(tab[idx(n,m)][h])   (TRANSPOSED for vector loads)
__global__ void bias16_kernel(const float* __restrict__ tab, float* __restrict__ b16) {
  int t = blockIdx.x * blockDim.x + threadIdx.x;
  if (t >= 16 * 64 * 64) return;
  int h = t >> 12, nm = t & 4095, m = nm >> 6, n = nm & 63;
  int idx = ((n >> 3) - (m >> 3) + 7) * 15 + ((n & 7) - (m & 7) + 7);
  float b = tab[idx * 16 + h];
  b16[t] = 16.0f / (1.0f + expf(-b));
}

// ---------------- m97-style bf16 GEMM (generic, swizzled): out-projection ----------
template <bool F32OUT>
__global__ __launch_bounds__(256) void gemm_bt(const u16* __restrict__ A,
                                               const u16* __restrict__ Bt,
                                               void* __restrict__ Cout,
                                               int M, int N) {
  __shared__ u16 lA[128 * 64];
  __shared__ u16 lB[128 * 64];
  const int tid = threadIdx.x;
  const int w = tid >> 6, l = tid & 63;
  const int lg = l >> 4, li = l & 15;
  const int nbn = N >> 7;
  const int nwg = gridDim.x;
  int bidx = blockIdx.x;
  int q = nwg >> 3, r = nwg & 7;
  int xcd = bidx & 7, pos = bidx >> 3;
  int swz = (xcd < r ? xcd * (q + 1) : r * (q + 1) + (xcd - r) * q) + pos;
  int bm = swz / nbn, bn = swz % nbn;
  const int wr = w >> 1, wc = w & 1;

  f32x4 acc[4][4];
#pragma unroll
  for (int i = 0; i < 4; i++)
#pragma unroll
    for (int j = 0; j < 4; j++) acc[i][j] = (f32x4){0.f, 0.f, 0.f, 0.f};

  const u16* Abase = A + (size_t)(bm * 128) * KDIM;
  const u16* Bbase = Bt + (size_t)(bn * 128) * KDIM;

#pragma unroll
  for (int k0 = 0; k0 < KDIM; k0 += 64) {
#pragma unroll
    for (int i = 0; i < 4; ++i) {
      int c = w * 256 + i * 64 + l;
      int row = c >> 3, kc = c & 7;
      int kcs = kc ^ (row & 7);
      gload16(Abase + (size_t)row * KDIM + k0 + kcs * 8, (u16*)lA + c * 8);
      gload16(Bbase + (size_t)row * KDIM + k0 + kcs * 8, (u16*)lB + c * 8);
    }
    __syncthreads();
#pragma unroll
    for (int kk = 0; kk < 2; ++kk) {
      bf16x8 af[4], bfr[4];
#pragma unroll
      for (int t = 0; t < 4; ++t) {
        int row = wr * 64 + t * 16 + li;
        af[t] = *(const bf16x8*)&lA[row * 64 + (((kk * 4 + lg) ^ (row & 7)) << 3)];
        int col = wc * 64 + t * 16 + li;
        bfr[t] = *(const bf16x8*)&lB[col * 64 + (((kk * 4 + lg) ^ (col & 7)) << 3)];
      }
#pragma unroll
      for (int tm = 0; tm < 4; ++tm)
#pragma unroll
        for (int tn = 0; tn < 4; ++tn)
          acc[tm][tn] = MFMA16(af[tm], bfr[tn], acc[tm][tn]);
    }
    __syncthreads();
  }
  int r0 = bm * 128 + wr * 64 + lg * 4;
  int c0 = bn * 128 + wc * 64 + li;
#pragma unroll
  for (int tm = 0; tm < 4; ++tm)
#pragma unroll
    for (int tn = 0; tn < 4; ++tn)
#pragma unroll
      for (int j = 0; j < 4; ++j) {
        size_t off = (size_t)(r0 + tm * 16 + j) * N + c0 + tn * 16;
        if (F32OUT)
          ((float*)Cout)[off] = acc[tm][tn][j];
        else
          ((u16*)Cout)[off] = f2bf(acc[tm][tn][j]);
      }
}

// ---------------- 128^2 q/k GEMM + fused cosine-norm + head-major store -----------
__global__ __launch_bounds__(256) void gemm_qk(const u16* __restrict__ A,
                                               const u16* __restrict__ Bt,
                                               u16* __restrict__ Cq,
                                               const float* __restrict__ lscale) {
  __shared__ u16 lds[128 * 136];
  u16* lA = lds;
  u16* lB = lds + 8192;
  const int tid = threadIdx.x;
  const int w = tid >> 6, l = tid & 63;
  const int lg = l >> 4, li = l & 15;
  const int nbn = 8;
  const int nwg = gridDim.x;
  int bidx = blockIdx.x;
  int q = nwg >> 3, r = nwg & 7;
  int xcd = bidx & 7, pos = bidx >> 3;
  int swz = (xcd < r ? xcd * (q + 1) : r * (q + 1) + (xcd - r) * q) + pos;
  int bm = swz / nbn, bn = swz % nbn;
  const int wr = w >> 1, wc = w & 1;

  f32x4 acc[4][4];
#pragma unroll
  for (int i = 0; i < 4; i++)
#pragma unroll
    for (int j = 0; j < 4; j++) acc[i][j] = (f32x4){0.f, 0.f, 0.f, 0.f};

  const u16* Abase = A + (size_t)(bm * 128) * KDIM;
  const u16* Bbase = Bt + (size_t)(bn * 128) * KDIM;

#pragma unroll
  for (int k0 = 0; k0 < KDIM; k0 += 64) {
#pragma unroll
    for (int i = 0; i < 4; ++i) {
      int c = w * 256 + i * 64 + l;
      int row = c >> 3, kc = c & 7;
      int kcs = kc ^ (row & 7);  // source pre-swizzle (rule 21)
      gload16(Abase + (size_t)row * KDIM + k0 + kcs * 8, lA + c * 8);
      gload16(Bbase + (size_t)row * KDIM + k0 + kcs * 8, lB + c * 8);
    }
    __syncthreads();
#pragma unroll
    for (int kk = 0; kk < 2; ++kk) {
      bf16x8 af[4], bfr[4];
#pragma unroll
      for (int t = 0; t < 4; ++t) {
        int row = wr * 64 + t * 16 + li;
        af[t] = *(const bf16x8*)&lA[row * 64 + (((kk * 4 + lg) ^ (row & 7)) << 3)];
        int col = wc * 64 + t * 16 + li;
        bfr[t] = *(const bf16x8*)&lB[col * 64 + (((kk * 4 + lg) ^ (col & 7)) << 3)];
      }
#pragma unroll
      for (int tm = 0; tm < 4; ++tm)
#pragma unroll
        for (int tn = 0; tn < 4; ++tn)
          acc[tm][tn] = MFMA16(af[tm], bfr[tn], acc[tm][tn]);
    }
    __syncthreads();
  }

  const int s_t = bn >> 2;          // 0=q 1=k
  const int hq = (bn & 3) * 4;
  float scv[2];
  if (s_t == 0) {
    scv[0] = __expf(fminf(lscale[hq + wc * 2 + 0], 4.6051702f));
    scv[1] = __expf(fminf(lscale[hq + wc * 2 + 1], 4.6051702f));
  } else {
    scv[0] = scv[1] = 1.0f;
  }
#pragma unroll
  for (int tm = 0; tm < 4; ++tm)
#pragma unroll
    for (int g = 0; g < 2; ++g) {
      f32x4 s2;
#pragma unroll
      for (int j = 0; j < 4; ++j)
        s2[j] = acc[tm][2 * g][j] * acc[tm][2 * g][j] +
                acc[tm][2 * g + 1][j] * acc[tm][2 * g + 1][j];
#pragma unroll
      for (int m = 1; m <= 8; m <<= 1)
#pragma unroll
        for (int j = 0; j < 4; ++j) s2[j] += __shfl_xor(s2[j], m);
#pragma unroll
      for (int j = 0; j < 4; ++j) {
        float rn = scv[g] / fmaxf(sqrtf(s2[j]), 1e-12f);
        acc[tm][2 * g][j] *= rn;
        acc[tm][2 * g + 1][j] *= rn;
      }
    }
  u16* ct = lds;
#pragma unroll
  for (int tm = 0; tm < 4; ++tm)
#pragma unroll
    for (int tn = 0; tn < 4; ++tn)
#pragma unroll
      for (int j = 0; j < 4; ++j)
        ct[(wr * 64 + tm * 16 + lg * 4 + j) * 136 + wc * 64 + tn * 16 + li] =
            f2bf(acc[tm][tn][j]);
  __syncthreads();
  {
    int rr = tid >> 2;
    int c8 = (tid & 3) * 8;
#pragma unroll
    for (int bh = 0; bh < 2; ++bh)
#pragma unroll
      for (int ht = 0; ht < 4; ++ht) {
        bf16x8 v = *(const bf16x8*)(ct + (bh * 64 + rr) * 136 + ht * 32 + c8);
        size_t base = ((size_t)(s_t * 16 + hq + ht) * 2048 + (bm * 2 + bh)) * 2048;
        *(bf16x8*)(Cq + base + rr * 32 + c8) = v;
      }
  }
}

// ---------------- 128^2 V GEMM + transposed store [32+h][b][d][n] -----------------
__global__ __launch_bounds__(256) void gemm_v(const u16* __restrict__ A,
                                              const u16* __restrict__ Bt,
                                              u16* __restrict__ Cq) {
  __shared__ u16 lds[128 * 136];
  u16* lA = lds;
  u16* lB = lds + 8192;
  const int tid = threadIdx.x;
  const int w = tid >> 6, l = tid & 63;
  const int lg = l >> 4, li = l & 15;
  const int nbn = 4;
  const int nwg = gridDim.x;
  int bidx = blockIdx.x;
  int q = nwg >> 3, r = nwg & 7;
  int xcd = bidx & 7, pos = bidx >> 3;
  int swz = (xcd < r ? xcd * (q + 1) : r * (q + 1) + (xcd - r) * q) + pos;
  int bm = swz / nbn, bn = swz % nbn;
  const int wr = w >> 1, wc = w & 1;

  f32x4 acc[4][4];
#pragma unroll
  for (int i = 0; i < 4; i++)
#pragma unroll
    for (int j = 0; j < 4; j++) acc[i][j] = (f32x4){0.f, 0.f, 0.f, 0.f};

  const u16* Abase = A + (size_t)(bm * 128) * KDIM;
  const u16* Bbase = Bt + (size_t)(bn * 128) * KDIM;

#pragma unroll
  for (int k0 = 0; k0 < KDIM; k0 += 64) {
#pragma unroll
    for (int i = 0; i < 4; ++i) {
      int c = w * 256 + i * 64 + l;
      int row = c >> 3, kc = c & 7;
      int kcs = kc ^ (row & 7);
      gload16(Abase + (size_t)row * KDIM + k0 + kcs * 8, lA + c * 8);
      gload16(Bbase + (size_t)row * KDIM + k0 + kcs * 8, lB + c * 8);
    }
    __syncthreads();
#pragma unroll
    for (int kk = 0; kk < 2; ++kk) {
      bf16x8 af[4], bfr[4];
#pragma unroll
      for (int t = 0; t < 4; ++t) {
        int row = wr * 64 + t * 16 + li;
        af[t] = *(const bf16x8*)&lA[row * 64 + (((kk * 4 + lg) ^ (row & 7)) << 3)];
        int col = wc * 64 + t * 16 + li;
        bfr[t] = *(const bf16x8*)&lB[col * 64 + (((kk * 4 + lg) ^ (col & 7)) << 3)];
      }
#pragma unroll
      for (int tm = 0; tm < 4; ++tm)
#pragma unroll
        for (int tn = 0; tn < 4; ++tn)
          acc[tm][tn] = MFMA16(af[tm], bfr[tn], acc[tm][tn]);
    }
    __syncthreads();
  }

  const int hq = bn * 4;
  u16* ctT = lds;
#pragma unroll
  for (int tm = 0; tm < 4; ++tm)
#pragma unroll
    for (int tn = 0; tn < 4; ++tn)
#pragma unroll
      for (int j = 0; j < 4; ++j)
        ctT[(wc * 64 + tn * 16 + li) * 136 + wr * 64 + tm * 16 + lg * 4 + j] =
            f2bf(acc[tm][tn][j]);
  __syncthreads();
#pragma unroll
  for (int r2 = 0; r2 < 8; ++r2) {
    int id = r2 * 256 + tid;
    int colc = id >> 4;
    int seg = id & 15;
    bf16x8 v = *(const bf16x8*)&ctT[colc * 136 + seg * 8];
    int ht = colc >> 5, d = colc & 31;
    int wi = seg >> 3, n0 = (seg & 7) * 8;
    size_t base = ((size_t)(32 + hq + ht) * 2048 + (bm * 2 + wi)) * 2048;
    *(bf16x8*)(Cq + base + d * 64 + n0) = v;
  }
}

// ---------------- attention-only: q,k head-major [h][b][n][d]; V^T [h][b][d][n] ----
// Two-phase softmax (vals in regs) + n-major compact P16r [16h][64n][20m] u16
// (aliases S after a barrier) -> PV P-frags via 2x ds_read_b64, conflict-free.
__global__ __launch_bounds__(512, 2) void attn2(const u16* __restrict__ qkv,
                                                const float* __restrict__ maskT,
                                                const float* __restrict__ bias16T,
                                                u16* __restrict__ aout) {
  __shared__ float S[16 * 1088];     // [h][m(16)][68-pad n] f32 = 69,632 B
  u16* P16r = (u16*)S;               // phase B alias: [16h][64n][20m] u16 = 40,960 B
  float* ob = S;                     // epilogue alias [16][516] f32
  const int tid = threadIdx.x;
  const int w = tid >> 6, l = tid & 63;
  const int lg = l >> 4, li = l & 15;
  const int b = blockIdx.x, wm = b & 63;
  const float* maskT_w = maskT + wm * 4096;

  // hoist Q fragments (loaded once, used in all 4 chunks)
  bf16x8 qfr[2][4];
#pragma unroll
  for (int hp = 0; hp < 2; ++hp) {
    const u16* qb = qkv + ((size_t)(w + hp * 8) * 2048 + b) * 2048;
#pragma unroll
    for (int tn = 0; tn < 4; ++tn)
      qfr[hp][tn] = *(const bf16x8*)(qb + (tn * 16 + li) * 32 + lg * 8);
  }

  f32x4 oacc[2][4][2];
#pragma unroll
  for (int hp = 0; hp < 2; ++hp)
#pragma unroll
    for (int i = 0; i < 4; ++i) {
      oacc[hp][i][0] = (f32x4){0.f, 0.f, 0.f, 0.f};
      oacc[hp][i][1] = (f32x4){0.f, 0.f, 0.f, 0.f};
    }

#pragma unroll
  for (int c = 0; c < 4; ++c) {
    // ---- QK^T chunk (16 keys) + bias + mask -> S (float4 loads, b128 writes) ----
#pragma unroll
    for (int hp = 0; hp < 2; ++hp) {
      int h = w + hp * 8;
      const u16* kb = qkv + ((size_t)(16 + h) * 2048 + b) * 2048;
      const float* biasT_h = bias16T + h * 4096;
      bf16x8 kfc = *(const bf16x8*)(kb + (c * 16 + li) * 32 + lg * 8);
      int mg = c * 16 + li;
#pragma unroll
      for (int tn = 0; tn < 4; ++tn) {
        f32x4 z = {0.f, 0.f, 0.f, 0.f};
        f32x4 s = MFMA16(qfr[hp][tn], kfc, z);
        float4v b4 = *(const float4v*)(biasT_h + mg * 64 + tn * 16 + lg * 4);
        float4v m4 = *(const float4v*)(maskT_w + mg * 64 + tn * 16 + lg * 4);
        *(float4v*)&S[h * 1088 + li * 68 + tn * 16 + lg * 4] = s + b4 + m4;
      }
    }
    __syncthreads();
    // ---- softmax phase A: read S into regs, exp + inv (no LDS writes yet) ----
    float vals[2][16];
    float inv[2];
#pragma unroll
    for (int pp = 0; pp < 2; ++pp) {
      int p = tid + pp * 512;
      int base = (p >> 6) * 68 + (p & 63);
      float mx = -3.0e38f;
#pragma unroll
      for (int hh = 0; hh < 16; ++hh) {
        vals[pp][hh] = S[hh * 1088 + base];
        mx = fmaxf(mx, vals[pp][hh]);
      }
      float sum = 0.f;
#pragma unroll
      for (int hh = 0; hh < 16; ++hh) {
        float e = __expf(vals[pp][hh] - mx);
        vals[pp][hh] = e;
        sum += e;
      }
      inv[pp] = 1.0f / sum;
    }
    __syncthreads();  // all S reads done; safe to overwrite with P16r
    // ---- softmax phase B: write compact n-major P16r[h][n][20m] ----
#pragma unroll
    for (int pp = 0; pp < 2; ++pp) {
      int p = tid + pp * 512;
      int m = p >> 6, n = p & 63;
#pragma unroll
      for (int hh = 0; hh < 16; ++hh)
        P16r[hh * 1280 + n * 20 + m] = f2bf(vals[pp][hh] * inv[pp]);
    }
    __syncthreads();
    // ---- PV (K=32 MFMA, upper 16 keys zero); P via b64, V^T via b128 ----
#pragma unroll
    for (int hp = 0; hp < 2; ++hp) {
      int h = w + hp * 8;
      const u16* vbT = qkv + ((size_t)(32 + h) * 2048 + b) * 2048;
      bf16x8 vf[2];
      if (lg < 2) {
#pragma unroll
        for (int td = 0; td < 2; ++td)
          vf[td] = *(const bf16x8*)(vbT + (td * 16 + li) * 64 + c * 16 + lg * 8);
      } else {
#pragma unroll
        for (int td = 0; td < 2; ++td)
#pragma unroll
          for (int e = 0; e < 8; ++e) vf[td][e] = 0;
      }
#pragma unroll
      for (int tn = 0; tn < 4; ++tn) {
        bf16x8 pf;
        if (lg < 2) {
          const u16* pb = P16r + h * 1280 + (tn * 16 + li) * 20 + lg * 8;
          bf16x4 plo = *(const bf16x4*)pb;
          bf16x4 phi = *(const bf16x4*)(pb + 4);
          pf[0] = plo[0]; pf[1] = plo[1]; pf[2] = plo[2]; pf[3] = plo[3];
          pf[4] = phi[0]; pf[5] = phi[1]; pf[6] = phi[2]; pf[7] = phi[3];
        } else {
#pragma unroll
          for (int e = 0; e < 8; ++e) pf[e] = 0;
        }
        oacc[hp][tn][0] = MFMA16(pf, vf[0], oacc[hp][tn][0]);
        oacc[hp][tn][1] = MFMA16(pf, vf[1], oacc[hp][tn][1]);
      }
    }
    __syncthreads();  // P16r reads done; next chunk overwrites S region
  }

  // ---- epilogue: 4 row-passes through ob, coalesced stores ----
#pragma unroll
  for (int tn = 0; tn < 4; ++tn) {
#pragma unroll
    for (int hp = 0; hp < 2; ++hp) {
      int h = w + hp * 8;
#pragma unroll
      for (int td = 0; td < 2; ++td)
#pragma unroll
        for (int j = 0; j < 4; ++j)
          ob[(lg * 4 + j) * 516 + h * 32 + td * 16 + li] = oacc[hp][tn][td][j];
    }
    __syncthreads();
    {
      int rr = tid >> 5, c16 = (tid & 31) * 16;
      const float* src = ob + rr * 516 + c16;
      u16* dst = aout + ((size_t)b * 64 + tn * 16 + rr) * 512 + c16;
#pragma unroll
      for (int half = 0; half < 2; ++half) {
        union { bf16x8 v; u16 u[8]; } o;
#pragma unroll
        for (int e = 0; e < 8; ++e) o.u[e] = f2bf(src[half * 8 + e]);
        *(bf16x8*)(dst + half * 8) = o.v;
      }
    }
    __syncthreads();
  }
}

extern "C" void kernel_launch(void* const* d_in, const int* in_sizes, int n_in,
                              void* d_out, int out_size, void* d_ws, size_t ws_size,
                              hipStream_t stream) {
  const float* x = (const float*)d_in[0];
  const float* mask = (const float*)d_in[1];
  const float* w_qkv = (const float*)d_in[2];
  const float* w_out = (const float*)d_in[3];
  const float* cpb_w1 = (const float*)d_in[4];
  const float* cpb_w2 = (const float*)d_in[5];
  const float* lscale = (const float*)d_in[6];
  float* out = (float*)d_out;

  char* ws = (char*)d_ws;
  u16* wqkvT = (u16*)ws;                          // 1,572,864 B
  u16* woutT = (u16*)(ws + 1572864ull);           // 524,288 B
  float* btab = (float*)(ws + 2097152ull);        // 16,384 B
  float* b16 = (float*)(ws + 2113536ull);         // 262,144 B (transposed [h][m][n])
  float* maskT = (float*)(ws + 2375680ull);       // 16,777,216 B ([w][m][n])
  u16* qkv_ws = (u16*)(ws + 19152896ull);         // 402,653,184 B (head-major / V^T)
  u16* xb = (u16*)(ws + 19152896ull + 402653184ull);  // 134,217,728 B
  u16* attn_out = xb;  // alias: xb dead after gemm_qk/gemm_v; attn2 runs after

  // prep
  transpose_kernel<<<(512 * 1536 + 255) / 256, 256, 0, stream>>>(w_qkv, wqkvT, 512, 1536);
  transpose_kernel<<<(512 * 512 + 255) / 256, 256, 0, stream>>>(w_out, woutT, 512, 512);
  bias_tab_kernel<<<(225 * 16 + 255) / 256, 256, 0, stream>>>(cpb_w1, cpb_w2, btab);
  bias16_kernel<<<(16 * 64 * 64 + 255) / 256, 256, 0, stream>>>(btab, b16);
  mask_t_kernel<<<(64 * 4096 + 255) / 256, 256, 0, stream>>>(mask, maskT);

  // x -> bf16
  convert_bf16_kernel<<<(131072 * 64 + 255) / 256, 256, 0, stream>>>(x, xb, 131072 * 64);

  // q/k GEMM (fused norm/scale, head-major) and V GEMM (transposed) — split kernels
  gemm_qk<<<8192, 256, 0, stream>>>(xb, wqkvT, qkv_ws, lscale);
  gemm_v<<<4096, 256, 0, stream>>>(xb, wqkvT + (size_t)1024 * 512, qkv_ws);

  // attention (reads qkv_ws, writes attn_out == xb)
  attn2<<<2048, 512, 0, stream>>>(qkv_ws, maskT, b16, attn_out);

  // out = attn_out @ w_out (fp32 stores)
  gemm_bt<true><<<4096, 256, 0, stream>>>(attn_out, woutT, out, 131072, 512);
}

// Round 22
// 813.065 us; speedup vs baseline: 1.3242x; 1.0445x over previous
//
#include <hip/hip_runtime.h>
#include <hip/hip_bf16.h>

typedef unsigned short u16;
typedef unsigned int u32;
typedef __attribute__((ext_vector_type(8))) short bf16x8;
typedef __attribute__((ext_vector_type(4))) short bf16x4;
typedef __attribute__((ext_vector_type(4))) float f32x4;
typedef __attribute__((ext_vector_type(4))) float float4v;

__device__ __forceinline__ float bf2f(u16 v) {
  union { u32 u; float f; } x; x.u = ((u32)v) << 16; return x.f;
}
__device__ __forceinline__ u16 f2bf(float f) {
  union { u32 u; float f; } x; x.f = f;
  return (u16)((x.u + 0x7fffu + ((x.u >> 16) & 1u)) >> 16);
}

__device__ __forceinline__ void gload16(const void* g, void* l) {
  __builtin_amdgcn_global_load_lds(
      (const __attribute__((address_space(1))) u32*)g,
      (__attribute__((address_space(3))) u32*)l, 16, 0, 0);
}

#define MFMA16(a, bfr, cacc) __builtin_amdgcn_mfma_f32_16x16x32_bf16((a), (bfr), (cacc), 0, 0, 0)

// K is compile-time everywhere (512) so the K-loop fully unrolls: staging bases are
// loop-invariant, per-iter +k0 folds into global_load imm offsets, LDS read addrs CSE.
constexpr int KDIM = 512;

// ---------------- prep kernels ----------------

__global__ void convert_bf16_kernel(const float* __restrict__ in,
                                    u16* __restrict__ out, int n8) {
  int t = blockIdx.x * blockDim.x + threadIdx.x;
  if (t >= n8) return;
  const float4v* p = (const float4v*)(in + (size_t)t * 8);
  float4v a = p[0], b = p[1];
  union { bf16x8 v; u16 s[8]; } o;
  o.s[0] = f2bf(a[0]); o.s[1] = f2bf(a[1]); o.s[2] = f2bf(a[2]); o.s[3] = f2bf(a[3]);
  o.s[4] = f2bf(b[0]); o.s[5] = f2bf(b[1]); o.s[6] = f2bf(b[2]); o.s[7] = f2bf(b[3]);
  *(bf16x8*)(out + (size_t)t * 8) = o.v;
}

__global__ void transpose_kernel(const float* __restrict__ in, u16* __restrict__ out,
                                 int R, int C) {
  int t = blockIdx.x * blockDim.x + threadIdx.x;
  if (t >= R * C) return;
  int c = t / R, r = t % R;
  out[t] = f2bf(in[r * C + c]);
}

// maskT[wm][m][n] = mask[wm][n][m]  (fp32, coalesced writes)
__global__ void mask_t_kernel(const float* __restrict__ in, float* __restrict__ out) {
  int t = blockIdx.x * blockDim.x + threadIdx.x;
  if (t >= 64 * 4096) return;
  int wm = t >> 12, rest = t & 4095, m = rest >> 6, n = rest & 63;
  out[t] = in[wm * 4096 + n * 64 + m];
}

__global__ void bias_tab_kernel(const float* __restrict__ w1, const float* __restrict__ w2,
                                float* __restrict__ tab) {
  int t = blockIdx.x * blockDim.x + threadIdx.x;
  if (t >= 225 * 16) return;
  int r = t >> 4, h = t & 15;
  int i = r / 15, j = r % 15;
  float gi = (float)(i - 7) * (8.0f / 7.0f);
  float gj = (float)(j - 7) * (8.0f / 7.0f);
  float si = (gi > 0.f) ? 1.f : ((gi < 0.f) ? -1.f : 0.f);
  float sj = (gj > 0.f) ? 1.f : ((gj < 0.f) ? -1.f : 0.f);
  float t0 = si * log2f(fabsf(gi) + 1.0f) * (1.0f / 3.0f);
  float t1 = sj * log2f(fabsf(gj) + 1.0f) * (1.0f / 3.0f);
  float acc = 0.f;
  for (int k = 0; k < 512; ++k) {
    float a = t0 * w1[k] + t1 * w1[512 + k];
    float hs = a * fminf(fmaxf(a + 3.f, 0.f), 6.f) * (1.f / 6.f);
    acc += hs * w2[k * 16 + h];
  }
  tab[t] = acc;
}

// bias16T[h][m][n] = 16*sigmoid(tab[idx(n,m)][h])   (TRANSPOSED for vector loads)
__global__ void bias16_kernel(const float* __restrict__ tab, float* __restrict__ b16) {
  int t = blockIdx.x * blockDim.x + threadIdx.x;
  if (t >= 16 * 64 * 64) return;
  int h = t >> 12, nm = t & 4095, m = nm >> 6, n = nm & 63;
  int idx = ((n >> 3) - (m >> 3) + 7) * 15 + ((n & 7) - (m & 7) + 7);
  float b = tab[idx * 16 + h];
  b16[t] = 16.0f / (1.0f + expf(-b));
}

// ---------------- m97-style bf16 GEMM (generic, swizzled): out-projection ----------
template <bool F32OUT>
__global__ __launch_bounds__(256) void gemm_bt(const u16* __restrict__ A,
                                               const u16* __restrict__ Bt,
                                               void* __restrict__ Cout,
                                               int M, int N) {
  __shared__ u16 lA[128 * 64];
  __shared__ u16 lB[128 * 64];
  const int tid = threadIdx.x;
  const int w = tid >> 6, l = tid & 63;
  const int lg = l >> 4, li = l & 15;
  const int nbn = N >> 7;
  const int nwg = gridDim.x;
  int bidx = blockIdx.x;
  int q = nwg >> 3, r = nwg & 7;
  int xcd = bidx & 7, pos = bidx >> 3;
  int swz = (xcd < r ? xcd * (q + 1) : r * (q + 1) + (xcd - r) * q) + pos;
  int bm = swz / nbn, bn = swz % nbn;
  const int wr = w >> 1, wc = w & 1;

  f32x4 acc[4][4];
#pragma unroll
  for (int i = 0; i < 4; i++)
#pragma unroll
    for (int j = 0; j < 4; j++) acc[i][j] = (f32x4){0.f, 0.f, 0.f, 0.f};

  const u16* Abase = A + (size_t)(bm * 128) * KDIM;
  const u16* Bbase = Bt + (size_t)(bn * 128) * KDIM;

#pragma unroll
  for (int k0 = 0; k0 < KDIM; k0 += 64) {
#pragma unroll
    for (int i = 0; i < 4; ++i) {
      int c = w * 256 + i * 64 + l;
      int row = c >> 3, kc = c & 7;
      int kcs = kc ^ (row & 7);
      gload16(Abase + (size_t)row * KDIM + k0 + kcs * 8, (u16*)lA + c * 8);
      gload16(Bbase + (size_t)row * KDIM + k0 + kcs * 8, (u16*)lB + c * 8);
    }
    __syncthreads();
#pragma unroll
    for (int kk = 0; kk < 2; ++kk) {
      bf16x8 af[4], bfr[4];
#pragma unroll
      for (int t = 0; t < 4; ++t) {
        int row = wr * 64 + t * 16 + li;
        af[t] = *(const bf16x8*)&lA[row * 64 + (((kk * 4 + lg) ^ (row & 7)) << 3)];
        int col = wc * 64 + t * 16 + li;
        bfr[t] = *(const bf16x8*)&lB[col * 64 + (((kk * 4 + lg) ^ (col & 7)) << 3)];
      }
#pragma unroll
      for (int tm = 0; tm < 4; ++tm)
#pragma unroll
        for (int tn = 0; tn < 4; ++tn)
          acc[tm][tn] = MFMA16(af[tm], bfr[tn], acc[tm][tn]);
    }
    __syncthreads();
  }
  int r0 = bm * 128 + wr * 64 + lg * 4;
  int c0 = bn * 128 + wc * 64 + li;
#pragma unroll
  for (int tm = 0; tm < 4; ++tm)
#pragma unroll
    for (int tn = 0; tn < 4; ++tn)
#pragma unroll
      for (int j = 0; j < 4; ++j) {
        size_t off = (size_t)(r0 + tm * 16 + j) * N + c0 + tn * 16;
        if (F32OUT)
          ((float*)Cout)[off] = acc[tm][tn][j];
        else
          ((u16*)Cout)[off] = f2bf(acc[tm][tn][j]);
      }
}

// ---------------- 128^2 q/k GEMM + fused cosine-norm + head-major store -----------
__global__ __launch_bounds__(256) void gemm_qk(const u16* __restrict__ A,
                                               const u16* __restrict__ Bt,
                                               u16* __restrict__ Cq,
                                               const float* __restrict__ lscale) {
  __shared__ u16 lds[128 * 136];
  u16* lA = lds;
  u16* lB = lds + 8192;
  const int tid = threadIdx.x;
  const int w = tid >> 6, l = tid & 63;
  const int lg = l >> 4, li = l & 15;
  const int nbn = 8;
  const int nwg = gridDim.x;
  int bidx = blockIdx.x;
  int q = nwg >> 3, r = nwg & 7;
  int xcd = bidx & 7, pos = bidx >> 3;
  int swz = (xcd < r ? xcd * (q + 1) : r * (q + 1) + (xcd - r) * q) + pos;
  int bm = swz / nbn, bn = swz % nbn;
  const int wr = w >> 1, wc = w & 1;

  f32x4 acc[4][4];
#pragma unroll
  for (int i = 0; i < 4; i++)
#pragma unroll
    for (int j = 0; j < 4; j++) acc[i][j] = (f32x4){0.f, 0.f, 0.f, 0.f};

  const u16* Abase = A + (size_t)(bm * 128) * KDIM;
  const u16* Bbase = Bt + (size_t)(bn * 128) * KDIM;

#pragma unroll
  for (int k0 = 0; k0 < KDIM; k0 += 64) {
#pragma unroll
    for (int i = 0; i < 4; ++i) {
      int c = w * 256 + i * 64 + l;
      int row = c >> 3, kc = c & 7;
      int kcs = kc ^ (row & 7);  // source pre-swizzle (rule 21)
      gload16(Abase + (size_t)row * KDIM + k0 + kcs * 8, lA + c * 8);
      gload16(Bbase + (size_t)row * KDIM + k0 + kcs * 8, lB + c * 8);
    }
    __syncthreads();
#pragma unroll
    for (int kk = 0; kk < 2; ++kk) {
      bf16x8 af[4], bfr[4];
#pragma unroll
      for (int t = 0; t < 4; ++t) {
        int row = wr * 64 + t * 16 + li;
        af[t] = *(const bf16x8*)&lA[row * 64 + (((kk * 4 + lg) ^ (row & 7)) << 3)];
        int col = wc * 64 + t * 16 + li;
        bfr[t] = *(const bf16x8*)&lB[col * 64 + (((kk * 4 + lg) ^ (col & 7)) << 3)];
      }
#pragma unroll
      for (int tm = 0; tm < 4; ++tm)
#pragma unroll
        for (int tn = 0; tn < 4; ++tn)
          acc[tm][tn] = MFMA16(af[tm], bfr[tn], acc[tm][tn]);
    }
    __syncthreads();
  }

  const int s_t = bn >> 2;          // 0=q 1=k
  const int hq = (bn & 3) * 4;
  float scv[2];
  if (s_t == 0) {
    scv[0] = __expf(fminf(lscale[hq + wc * 2 + 0], 4.6051702f));
    scv[1] = __expf(fminf(lscale[hq + wc * 2 + 1], 4.6051702f));
  } else {
    scv[0] = scv[1] = 1.0f;
  }
#pragma unroll
  for (int tm = 0; tm < 4; ++tm)
#pragma unroll
    for (int g = 0; g < 2; ++g) {
      f32x4 s2;
#pragma unroll
      for (int j = 0; j < 4; ++j)
        s2[j] = acc[tm][2 * g][j] * acc[tm][2 * g][j] +
                acc[tm][2 * g + 1][j] * acc[tm][2 * g + 1][j];
#pragma unroll
      for (int m = 1; m <= 8; m <<= 1)
#pragma unroll
        for (int j = 0; j < 4; ++j) s2[j] += __shfl_xor(s2[j], m);
#pragma unroll
      for (int j = 0; j < 4; ++j) {
        float rn = scv[g] / fmaxf(sqrtf(s2[j]), 1e-12f);
        acc[tm][2 * g][j] *= rn;
        acc[tm][2 * g + 1][j] *= rn;
      }
    }
  u16* ct = lds;
#pragma unroll
  for (int tm = 0; tm < 4; ++tm)
#pragma unroll
    for (int tn = 0; tn < 4; ++tn)
#pragma unroll
      for (int j = 0; j < 4; ++j)
        ct[(wr * 64 + tm * 16 + lg * 4 + j) * 136 + wc * 64 + tn * 16 + li] =
            f2bf(acc[tm][tn][j]);
  __syncthreads();
  {
    int rr = tid >> 2;
    int c8 = (tid & 3) * 8;
#pragma unroll
    for (int bh = 0; bh < 2; ++bh)
#pragma unroll
      for (int ht = 0; ht < 4; ++ht) {
        bf16x8 v = *(const bf16x8*)(ct + (bh * 64 + rr) * 136 + ht * 32 + c8);
        size_t base = ((size_t)(s_t * 16 + hq + ht) * 2048 + (bm * 2 + bh)) * 2048;
        *(bf16x8*)(Cq + base + rr * 32 + c8) = v;
      }
  }
}

// ---------------- 128^2 V GEMM + transposed store [32+h][b][d][n] -----------------
__global__ __launch_bounds__(256) void gemm_v(const u16* __restrict__ A,
                                              const u16* __restrict__ Bt,
                                              u16* __restrict__ Cq) {
  __shared__ u16 lds[128 * 136];
  u16* lA = lds;
  u16* lB = lds + 8192;
  const int tid = threadIdx.x;
  const int w = tid >> 6, l = tid & 63;
  const int lg = l >> 4, li = l & 15;
  const int nbn = 4;
  const int nwg = gridDim.x;
  int bidx = blockIdx.x;
  int q = nwg >> 3, r = nwg & 7;
  int xcd = bidx & 7, pos = bidx >> 3;
  int swz = (xcd < r ? xcd * (q + 1) : r * (q + 1) + (xcd - r) * q) + pos;
  int bm = swz / nbn, bn = swz % nbn;
  const int wr = w >> 1, wc = w & 1;

  f32x4 acc[4][4];
#pragma unroll
  for (int i = 0; i < 4; i++)
#pragma unroll
    for (int j = 0; j < 4; j++) acc[i][j] = (f32x4){0.f, 0.f, 0.f, 0.f};

  const u16* Abase = A + (size_t)(bm * 128) * KDIM;
  const u16* Bbase = Bt + (size_t)(bn * 128) * KDIM;

#pragma unroll
  for (int k0 = 0; k0 < KDIM; k0 += 64) {
#pragma unroll
    for (int i = 0; i < 4; ++i) {
      int c = w * 256 + i * 64 + l;
      int row = c >> 3, kc = c & 7;
      int kcs = kc ^ (row & 7);
      gload16(Abase + (size_t)row * KDIM + k0 + kcs * 8, lA + c * 8);
      gload16(Bbase + (size_t)row * KDIM + k0 + kcs * 8, lB + c * 8);
    }
    __syncthreads();
#pragma unroll
    for (int kk = 0; kk < 2; ++kk) {
      bf16x8 af[4], bfr[4];
#pragma unroll
      for (int t = 0; t < 4; ++t) {
        int row = wr * 64 + t * 16 + li;
        af[t] = *(const bf16x8*)&lA[row * 64 + (((kk * 4 + lg) ^ (row & 7)) << 3)];
        int col = wc * 64 + t * 16 + li;
        bfr[t] = *(const bf16x8*)&lB[col * 64 + (((kk * 4 + lg) ^ (col & 7)) << 3)];
      }
#pragma unroll
      for (int tm = 0; tm < 4; ++tm)
#pragma unroll
        for (int tn = 0; tn < 4; ++tn)
          acc[tm][tn] = MFMA16(af[tm], bfr[tn], acc[tm][tn]);
    }
    __syncthreads();
  }

  const int hq = bn * 4;
  u16* ctT = lds;
#pragma unroll
  for (int tm = 0; tm < 4; ++tm)
#pragma unroll
    for (int tn = 0; tn < 4; ++tn)
#pragma unroll
      for (int j = 0; j < 4; ++j)
        ctT[(wc * 64 + tn * 16 + li) * 136 + wr * 64 + tm * 16 + lg * 4 + j] =
            f2bf(acc[tm][tn][j]);
  __syncthreads();
#pragma unroll
  for (int r2 = 0; r2 < 8; ++r2) {
    int id = r2 * 256 + tid;
    int colc = id >> 4;
    int seg = id & 15;
    bf16x8 v = *(const bf16x8*)&ctT[colc * 136 + seg * 8];
    int ht = colc >> 5, d = colc & 31;
    int wi = seg >> 3, n0 = (seg & 7) * 8;
    size_t base = ((size_t)(32 + hq + ht) * 2048 + (bm * 2 + wi)) * 2048;
    *(bf16x8*)(Cq + base + d * 64 + n0) = v;
  }
}

// ---------------- attention-only, critical-path-compressed ------------------------
// q,k head-major [h][b][n][d]; V^T [h][b][d][n].
// P16r [16h][64n][40m] u16 (own region, 16B-aligned rows): two 16-key chunks fill
// 32 P-slots, then ONE full-K=32 PV round (all lanes, pf = single ds_read_b128).
// Softmax is a single pass (no A/B split). Epilogue: single bf16 bounce o16[64][528].
// Barriers: 20 -> 11.  LDS: S 69,632 + P16r 81,920 = 151,552 B (1 block/CU as before).
__global__ __launch_bounds__(512, 2) void attn2(const u16* __restrict__ qkv,
                                                const float* __restrict__ maskT,
                                                const float* __restrict__ bias16T,
                                                u16* __restrict__ aout) {
  __shared__ float S[16 * 1088];            // [h][16m][68n] f32 = 69,632 B
  __shared__ __align__(16) u16 P16r[16 * 2560];  // [16h][64n][40m] = 81,920 B
  u16* o16 = (u16*)S;                       // epilogue alias [64][528] u16 = 67,584 B
  const int tid = threadIdx.x;
  const int w = tid >> 6, l = tid & 63;
  const int lg = l >> 4, li = l & 15;
  const int b = blockIdx.x, wm = b & 63;
  const float* maskT_w = maskT + wm * 4096;

  // hoist Q fragments (loaded once, used in all 4 chunks)
  bf16x8 qfr[2][4];
#pragma unroll
  for (int hp = 0; hp < 2; ++hp) {
    const u16* qb = qkv + ((size_t)(w + hp * 8) * 2048 + b) * 2048;
#pragma unroll
    for (int tn = 0; tn < 4; ++tn)
      qfr[hp][tn] = *(const bf16x8*)(qb + (tn * 16 + li) * 32 + lg * 8);
  }

  f32x4 oacc[2][4][2];
#pragma unroll
  for (int hp = 0; hp < 2; ++hp)
#pragma unroll
    for (int i = 0; i < 4; ++i) {
      oacc[hp][i][0] = (f32x4){0.f, 0.f, 0.f, 0.f};
      oacc[hp][i][1] = (f32x4){0.f, 0.f, 0.f, 0.f};
    }

#pragma unroll
  for (int c2 = 0; c2 < 2; ++c2) {  // two 32-key groups
#pragma unroll
    for (int half = 0; half < 2; ++half) {
      const int c = c2 * 2 + half;  // 16-key chunk
      // ---- QK^T chunk + bias + mask -> S (float4 loads, b128 writes) ----
#pragma unroll
      for (int hp = 0; hp < 2; ++hp) {
        int h = w + hp * 8;
        const u16* kb = qkv + ((size_t)(16 + h) * 2048 + b) * 2048;
        const float* biasT_h = bias16T + h * 4096;
        bf16x8 kfc = *(const bf16x8*)(kb + (c * 16 + li) * 32 + lg * 8);
        int mg = c * 16 + li;
#pragma unroll
        for (int tn = 0; tn < 4; ++tn) {
          f32x4 z = {0.f, 0.f, 0.f, 0.f};
          f32x4 s = MFMA16(qfr[hp][tn], kfc, z);
          float4v b4 = *(const float4v*)(biasT_h + mg * 64 + tn * 16 + lg * 4);
          float4v m4 = *(const float4v*)(maskT_w + mg * 64 + tn * 16 + lg * 4);
          *(float4v*)&S[h * 1088 + li * 68 + tn * 16 + lg * 4] = s + b4 + m4;
        }
      }
      __syncthreads();
      // ---- softmax over 16 heads (single pass): read S, write P16r slot ----
#pragma unroll
      for (int pp = 0; pp < 2; ++pp) {
        int p = tid + pp * 512;
        int m = p >> 6, n = p & 63;
        int base = m * 68 + n;
        float vals[16];
        float mx = -3.0e38f;
#pragma unroll
        for (int hh = 0; hh < 16; ++hh) {
          vals[hh] = S[hh * 1088 + base];
          mx = fmaxf(mx, vals[hh]);
        }
        float sum = 0.f;
#pragma unroll
        for (int hh = 0; hh < 16; ++hh) {
          float e = __expf(vals[hh] - mx);
          vals[hh] = e;
          sum += e;
        }
        float inv = 1.0f / sum;
        int slot = half * 16 + m;
#pragma unroll
        for (int hh = 0; hh < 16; ++hh)
          P16r[hh * 2560 + n * 40 + slot] = f2bf(vals[hh] * inv);
      }
      __syncthreads();  // S dead for next chunk; P16r half visible
    }
    // ---- PV: full K=32, all lanes; pf single b128, vf b128 ----
#pragma unroll
    for (int hp = 0; hp < 2; ++hp) {
      int h = w + hp * 8;
      const u16* vbT = qkv + ((size_t)(32 + h) * 2048 + b) * 2048;
      bf16x8 vf[2];
#pragma unroll
      for (int td = 0; td < 2; ++td)
        vf[td] = *(const bf16x8*)(vbT + (td * 16 + li) * 64 + c2 * 32 + lg * 8);
#pragma unroll
      for (int tn = 0; tn < 4; ++tn) {
        bf16x8 pf = *(const bf16x8*)&P16r[h * 2560 + (tn * 16 + li) * 40 + lg * 8];
        oacc[hp][tn][0] = MFMA16(pf, vf[0], oacc[hp][tn][0]);
        oacc[hp][tn][1] = MFMA16(pf, vf[1], oacc[hp][tn][1]);
      }
    }
    __syncthreads();  // P16r reads done before next group's softmax writes
  }

  // ---- epilogue: single bf16 bounce o16[64][528] (aliases dead S), 2 barriers ----
#pragma unroll
  for (int tn = 0; tn < 4; ++tn)
#pragma unroll
    for (int hp = 0; hp < 2; ++hp) {
      int h = w + hp * 8;
#pragma unroll
      for (int td = 0; td < 2; ++td)
#pragma unroll
        for (int j = 0; j < 4; ++j)
          o16[(tn * 16 + lg * 4 + j) * 528 + h * 32 + td * 16 + li] =
              f2bf(oacc[hp][tn][td][j]);
    }
  __syncthreads();
  {
    int row = tid >> 3, seg = tid & 7;
    u16* dst = aout + ((size_t)b * 64 + row) * 512;
    const u16* src = o16 + row * 528;
#pragma unroll
    for (int i = 0; i < 8; ++i) {
      int cc = (i * 8 + seg) * 8;  // u16 column of this 16B chunk
      *(bf16x8*)(dst + cc) = *(const bf16x8*)(src + cc);
    }
  }
}

extern "C" void kernel_launch(void* const* d_in, const int* in_sizes, int n_in,
                              void* d_out, int out_size, void* d_ws, size_t ws_size,
                              hipStream_t stream) {
  const float* x = (const float*)d_in[0];
  const float* mask = (const float*)d_in[1];
  const float* w_qkv = (const float*)d_in[2];
  const float* w_out = (const float*)d_in[3];
  const float* cpb_w1 = (const float*)d_in[4];
  const float* cpb_w2 = (const float*)d_in[5];
  const float* lscale = (const float*)d_in[6];
  float* out = (float*)d_out;

  char* ws = (char*)d_ws;
  u16* wqkvT = (u16*)ws;                          // 1,572,864 B
  u16* woutT = (u16*)(ws + 1572864ull);           // 524,288 B
  float* btab = (float*)(ws + 2097152ull);        // 16,384 B
  float* b16 = (float*)(ws + 2113536ull);         // 262,144 B (transposed [h][m][n])
  float* maskT = (float*)(ws + 2375680ull);       // 16,777,216 B ([w][m][n])
  u16* qkv_ws = (u16*)(ws + 19152896ull);         // 402,653,184 B (head-major / V^T)
  u16* xb = (u16*)(ws + 19152896ull + 402653184ull);  // 134,217,728 B
  u16* attn_out = xb;  // alias: xb dead after gemm_qk/gemm_v; attn2 runs after

  // prep
  transpose_kernel<<<(512 * 1536 + 255) / 256, 256, 0, stream>>>(w_qkv, wqkvT, 512, 1536);
  transpose_kernel<<<(512 * 512 + 255) / 256, 256, 0, stream>>>(w_out, woutT, 512, 512);
  bias_tab_kernel<<<(225 * 16 + 255) / 256, 256, 0, stream>>>(cpb_w1, cpb_w2, btab);
  bias16_kernel<<<(16 * 64 * 64 + 255) / 256, 256, 0, stream>>>(btab, b16);
  mask_t_kernel<<<(64 * 4096 + 255) / 256, 256, 0, stream>>>(mask, maskT);

  // x -> bf16
  convert_bf16_kernel<<<(131072 * 64 + 255) / 256, 256, 0, stream>>>(x, xb, 131072 * 64);

  // q/k GEMM (fused norm/scale, head-major) and V GEMM (transposed) — split kernels
  gemm_qk<<<8192, 256, 0, stream>>>(xb, wqkvT, qkv_ws, lscale);
  gemm_v<<<4096, 256, 0, stream>>>(xb, wqkvT + (size_t)1024 * 512, qkv_ws);

  // attention (reads qkv_ws, writes attn_out == xb)
  attn2<<<2048, 512, 0, stream>>>(qkv_ws, maskT, b16, attn_out);

  // out = attn_out @ w_out (fp32 stores)
  gemm_bt<true><<<4096, 256, 0, stream>>>(attn_out, woutT, out, 131072, 512);
}